// Round 1
// baseline (2422.036 us; speedup 1.0000x reference)
//
#include <hip/hip_runtime.h>
#include <math.h>

#define D 128
#define RPB 32

// ---------------------------------------------------------------------------
// prep_weights: fold linear layers.
//   Wqa = Wq @ Wa1[0:128]     bqa = bq @ Wa1[0:128] + ba1
//   Wka = Wk @ Wa1[128:256]   bka = bk @ Wa1[128:256]
//   Wva = Wv @ Wm1[0:128]     bva = bv @ Wm1[0:128] + bm1
// grid: 387 blocks x 128 threads (384 matrix-row blocks + 3 bias blocks)
// ---------------------------------------------------------------------------
__global__ void prep_weights(const float* __restrict__ Wq, const float* __restrict__ bq,
                             const float* __restrict__ Wk, const float* __restrict__ bk,
                             const float* __restrict__ Wv, const float* __restrict__ bv,
                             const float* __restrict__ Wa1, const float* __restrict__ ba1,
                             const float* __restrict__ Wm1, const float* __restrict__ bm1,
                             float* __restrict__ Wqa, float* __restrict__ Wka, float* __restrict__ Wva,
                             float* __restrict__ bqa, float* __restrict__ bka, float* __restrict__ bva)
{
    int b = blockIdx.x;
    int j = threadIdx.x;
    if (b < 384) {
        int which = b >> 7, i = b & 127;
        const float *A, *B; float *C;
        if (which == 0)      { A = Wq; B = Wa1;           C = Wqa; }
        else if (which == 1) { A = Wk; B = Wa1 + 128 * D; C = Wka; }
        else                 { A = Wv; B = Wm1;           C = Wva; }
        float acc = 0.f;
        for (int k = 0; k < D; k++) acc += A[i * D + k] * B[k * D + j];
        C[i * D + j] = acc;
    } else {
        int which = b - 384;
        const float *bias, *B, *extra; float *out;
        if (which == 0)      { bias = bq; B = Wa1;           out = bqa; extra = ba1; }
        else if (which == 1) { bias = bk; B = Wa1 + 128 * D; out = bka; extra = nullptr; }
        else                 { bias = bv; B = Wm1;           out = bva; extra = bm1; }
        float acc = extra ? extra[j] : 0.f;
        for (int k = 0; k < D; k++) acc += bias[k] * B[k * D + j];
        out[j] = acc;
    }
}

// ---------------------------------------------------------------------------
// prep_bounds: e(a)=relu(a*We1+be1)@We2+be2 is piecewise-linear in scalar a.
// Compute & sort the 128 ReLU breakpoints clipped to [0,1] (edge_attr range).
// bounds[0]=0, bounds[1..128]=sorted thresholds, bounds[129]=1.
// single block x 128 threads, bitonic sort in LDS.
// ---------------------------------------------------------------------------
__global__ void prep_bounds(const float* __restrict__ We1, const float* __restrict__ be1,
                            float* __restrict__ bounds)
{
    __shared__ float sb[128];
    int j = threadIdx.x;
    float w = We1[j], b = be1[j];
    float t = (w != 0.f) ? (-b / w) : 2.f;
    t = fminf(fmaxf(t, 0.f), 1.f);
    sb[j] = t;
    __syncthreads();
    for (int k = 2; k <= 128; k <<= 1)
        for (int jj = k >> 1; jj > 0; jj >>= 1) {
            int ixj = j ^ jj;
            if (ixj > j) {
                float a = sb[j], c = sb[ixj];
                bool up = ((j & k) == 0);
                if (up ? (a > c) : (a < c)) { sb[j] = c; sb[ixj] = a; }
            }
            __syncthreads();
        }
    if (j == 0) { bounds[0] = 0.f; bounds[129] = 1.f; }
    bounds[1 + j] = sb[j];
}

// ---------------------------------------------------------------------------
// prep_tables: per interval i, the active ReLU set is fixed; build
//   e(a) = a*Ae + Be  (Be includes be2), then project:
//   Aa[i] = Ae@Wa1_e, Ba[i] = Be@Wa1_e, Am[i] = Ae@Wm1_e, Bm[i] = Be@Wm1_e
// grid: 129 blocks (intervals) x 128 threads (output dim)
// ---------------------------------------------------------------------------
__global__ void prep_tables(const float* __restrict__ We1, const float* __restrict__ be1,
                            const float* __restrict__ We2, const float* __restrict__ be2,
                            const float* __restrict__ Wa1, const float* __restrict__ Wm1,
                            const float* __restrict__ bounds,
                            float* __restrict__ Aa, float* __restrict__ Ba,
                            float* __restrict__ Am, float* __restrict__ Bm)
{
    int i = blockIdx.x;   // interval 0..128
    int j = threadIdx.x;  // output dim
    __shared__ float Ae[128], Be[128];
    float m = 0.5f * (bounds[i] + bounds[i + 1]);
    float ae = 0.f, be = 0.f;
    for (int k = 0; k < 128; k++) {
        float w = We1[k], b = be1[k];
        if (m * w + b > 0.f) { ae += w * We2[k * D + j]; be += b * We2[k * D + j]; }
    }
    be += be2[j];
    Ae[j] = ae; Be[j] = be;
    __syncthreads();
    float aa = 0.f, ba = 0.f, am = 0.f, bm = 0.f;
    for (int l = 0; l < 128; l++) {
        float ael = Ae[l], bel = Be[l];
        float wa = Wa1[(256 + l) * D + j];
        float wm = Wm1[(128 + l) * D + j];
        aa += ael * wa; ba += bel * wa;
        am += ael * wm; bm += bel * wm;
    }
    Aa[i * D + j] = aa; Ba[i * D + j] = ba;
    Am[i * D + j] = am; Bm[i * D + j] = bm;
}

// ---------------------------------------------------------------------------
// node_gemm: qa/ka/va = h @ {Wqa,Wka,Wva} + bias.  RPB rows per 256-thr block.
// ---------------------------------------------------------------------------
__global__ __launch_bounds__(256) void node_gemm(
    const float* __restrict__ h, int N,
    const float* __restrict__ Wqa, const float* __restrict__ Wka, const float* __restrict__ Wva,
    const float* __restrict__ bqa, const float* __restrict__ bka, const float* __restrict__ bva,
    float* __restrict__ qa, float* __restrict__ ka, float* __restrict__ va)
{
    __shared__ float hs[RPB][D];
    int r0 = blockIdx.x * RPB;
    int t = threadIdx.x;
    for (int x = t; x < RPB * D; x += 256) {
        int r = x >> 7, cc = x & 127;
        hs[r][cc] = (r0 + r < N) ? h[(size_t)(r0 + r) * D + cc] : 0.f;
    }
    __syncthreads();
    int c = t & 127;
    int half = t >> 7;
    float acc0[16], acc1[16], acc2[16];
#pragma unroll
    for (int r = 0; r < 16; r++) { acc0[r] = 0.f; acc1[r] = 0.f; acc2[r] = 0.f; }
    for (int k = 0; k < D; k++) {
        float w0 = Wqa[k * D + c], w1 = Wka[k * D + c], w2 = Wva[k * D + c];
#pragma unroll
        for (int r = 0; r < 16; r++) {
            float hv = hs[half * 16 + r][k];
            acc0[r] += hv * w0; acc1[r] += hv * w1; acc2[r] += hv * w2;
        }
    }
    float b0 = bqa[c], b1 = bka[c], b2 = bva[c];
#pragma unroll
    for (int r = 0; r < 16; r++) {
        int row = r0 + half * 16 + r;
        if (row < N) {
            qa[(size_t)row * D + c] = acc0[r] + b0;
            ka[(size_t)row * D + c] = acc1[r] + b1;
            va[(size_t)row * D + c] = acc2[r] + b2;
        }
    }
}

// ordered-uint mapping for float atomicMax
__device__ inline unsigned f2u_ord(float f) {
    unsigned u = __float_as_uint(f);
    return (u & 0x80000000u) ? ~u : (u | 0x80000000u);
}
__device__ inline float u2f_ord(unsigned u) {
    return (u & 0x80000000u) ? __uint_as_float(u ^ 0x80000000u) : __uint_as_float(~u);
}

// ---------------------------------------------------------------------------
// edge_logits: 16 lanes per edge. logit = relu(qa[col]+ka[row]+a*Aa+Ba).Wa2+ba2
// atomicMax into segmax (ordered-uint).
// ---------------------------------------------------------------------------
__global__ __launch_bounds__(256) void edge_logits(
    const int* __restrict__ ei, const float* __restrict__ eattr, int E,
    const float* __restrict__ qa, const float* __restrict__ ka,
    const float* __restrict__ Aa, const float* __restrict__ Ba,
    const float* __restrict__ Wa2, const float* __restrict__ ba2,
    const float* __restrict__ bounds,
    float* __restrict__ logits, unsigned* __restrict__ segmax)
{
    __shared__ float b[130];
    int t = threadIdx.x;
    if (t < 130) b[t] = bounds[t];
    __syncthreads();
    int g = t >> 4, l = t & 15;
    int e = blockIdx.x * 16 + g;
    if (e >= E) return;
    int row = ei[e], col = ei[E + e];
    float a = eattr[e];
    int lo = 0, hi = 128;
    while (lo < hi) { int mid = (lo + hi + 1) >> 1; if (b[mid] <= a) lo = mid; else hi = mid - 1; }
    int i = lo;
    int d = l * 8;
    const float4* q4 = (const float4*)(qa + (size_t)col * D + d);
    const float4* k4 = (const float4*)(ka + (size_t)row * D + d);
    const float4* A4 = (const float4*)(Aa + i * D + d);
    const float4* B4 = (const float4*)(Ba + i * D + d);
    const float4* w4 = (const float4*)(Wa2 + d);
    float part = 0.f;
#pragma unroll
    for (int p = 0; p < 2; p++) {
        float4 qv = q4[p], kv = k4[p], Av = A4[p], Bv = B4[p], wv = w4[p];
        part += fmaxf(qv.x + kv.x + a * Av.x + Bv.x, 0.f) * wv.x;
        part += fmaxf(qv.y + kv.y + a * Av.y + Bv.y, 0.f) * wv.y;
        part += fmaxf(qv.z + kv.z + a * Av.z + Bv.z, 0.f) * wv.z;
        part += fmaxf(qv.w + kv.w + a * Av.w + Bv.w, 0.f) * wv.w;
    }
#pragma unroll
    for (int s = 1; s < 16; s <<= 1) part += __shfl_xor(part, s, 64);
    if (l == 0) {
        float logit = part + ba2[0];
        logits[e] = logit;
        atomicMax(segmax + col, f2u_ord(logit));
    }
}

// ---------------------------------------------------------------------------
// edge_expsum: ex = exp(logit - segmax[col]); atomicAdd segsum[col].
// ---------------------------------------------------------------------------
__global__ __launch_bounds__(256) void edge_expsum(
    const int* __restrict__ ei, int E,
    const float* __restrict__ logits, const unsigned* __restrict__ segmax,
    float* __restrict__ ex, float* __restrict__ segsum)
{
    int e = blockIdx.x * 256 + threadIdx.x;
    if (e >= E) return;
    int col = ei[E + e];
    float m = u2f_ord(segmax[col]);
    float x = expf(logits[e] - m);
    ex[e] = x;
    atomicAdd(segsum + col, x);
}

// ---------------------------------------------------------------------------
// edge_msg: w = ex/(segsum+1e-16); hid = silu(va[row]+a*Am+Bm);
// atomicAdd S[col] += w*hid.   (Wm2 matvec deferred to node_out since
// sum_e w_e*(x@Wm2+bm2) = (sum w_e x)@Wm2 + (sum w_e)*bm2.)
// ---------------------------------------------------------------------------
__global__ __launch_bounds__(256) void edge_msg(
    const int* __restrict__ ei, const float* __restrict__ eattr, int E,
    const float* __restrict__ va, const float* __restrict__ Am, const float* __restrict__ Bm,
    const float* __restrict__ bounds, const float* __restrict__ ex, const float* __restrict__ segsum,
    float* __restrict__ S)
{
    __shared__ float b[130];
    int t = threadIdx.x;
    if (t < 130) b[t] = bounds[t];
    __syncthreads();
    int g = t >> 4, l = t & 15;
    int e = blockIdx.x * 16 + g;
    if (e >= E) return;
    int row = ei[e], col = ei[E + e];
    float a = eattr[e];
    int lo = 0, hi = 128;
    while (lo < hi) { int mid = (lo + hi + 1) >> 1; if (b[mid] <= a) lo = mid; else hi = mid - 1; }
    int i = lo;
    float w = ex[e] / (segsum[col] + 1e-16f);
    int d = l * 8;
    const float4* v4 = (const float4*)(va + (size_t)row * D + d);
    const float4* A4 = (const float4*)(Am + i * D + d);
    const float4* B4 = (const float4*)(Bm + i * D + d);
    float* Sp = S + (size_t)col * D + d;
#pragma unroll
    for (int p = 0; p < 2; p++) {
        float4 vv = v4[p], Av = A4[p], Bv = B4[p];
        float x0 = vv.x + a * Av.x + Bv.x;
        float x1 = vv.y + a * Av.y + Bv.y;
        float x2 = vv.z + a * Av.z + Bv.z;
        float x3 = vv.w + a * Av.w + Bv.w;
        float s0 = x0 / (1.f + expf(-x0));
        float s1 = x1 / (1.f + expf(-x1));
        float s2 = x2 / (1.f + expf(-x2));
        float s3 = x3 / (1.f + expf(-x3));
        atomicAdd(Sp + p * 4 + 0, w * s0);
        atomicAdd(Sp + p * 4 + 1, w * s1);
        atomicAdd(Sp + p * 4 + 2, w * s2);
        atomicAdd(Sp + p * 4 + 3, w * s3);
    }
}

// ---------------------------------------------------------------------------
// node_out: out = h + S@Wm2 + bm2 * (segsum/(segsum+1e-16))
// ---------------------------------------------------------------------------
__global__ __launch_bounds__(256) void node_out(
    const float* __restrict__ h, int N,
    const float* __restrict__ S, const float* __restrict__ Wm2, const float* __restrict__ bm2,
    const float* __restrict__ segsum, float* __restrict__ out)
{
    __shared__ float Ss[RPB][D];
    int r0 = blockIdx.x * RPB;
    int t = threadIdx.x;
    for (int x = t; x < RPB * D; x += 256) {
        int r = x >> 7, cc = x & 127;
        Ss[r][cc] = (r0 + r < N) ? S[(size_t)(r0 + r) * D + cc] : 0.f;
    }
    __syncthreads();
    int c = t & 127, half = t >> 7;
    float acc[16];
#pragma unroll
    for (int r = 0; r < 16; r++) acc[r] = 0.f;
    for (int k = 0; k < D; k++) {
        float w = Wm2[k * D + c];
#pragma unroll
        for (int r = 0; r < 16; r++) acc[r] += Ss[half * 16 + r][k] * w;
    }
    float bb = bm2[c];
#pragma unroll
    for (int r = 0; r < 16; r++) {
        int row = r0 + half * 16 + r;
        if (row < N) {
            float ws = segsum[row];
            ws = ws / (ws + 1e-16f);
            out[(size_t)row * D + c] = h[(size_t)row * D + c] + acc[r] + bb * ws;
        }
    }
}

__global__ void copy_pos(const float* __restrict__ pos, int n, float* __restrict__ out)
{
    int i = blockIdx.x * 256 + threadIdx.x;
    if (i < n) out[i] = pos[i];
}

extern "C" void kernel_launch(void* const* d_in, const int* in_sizes, int n_in,
                              void* d_out, int out_size, void* d_ws, size_t ws_size,
                              hipStream_t stream)
{
    const float* h     = (const float*)d_in[0];
    const float* pos   = (const float*)d_in[1];
    const int*   ei    = (const int*)d_in[2];
    const float* eattr = (const float*)d_in[3];
    const float* Wq  = (const float*)d_in[4];  const float* bq  = (const float*)d_in[5];
    const float* Wk  = (const float*)d_in[6];  const float* bk  = (const float*)d_in[7];
    const float* Wv  = (const float*)d_in[8];  const float* bv  = (const float*)d_in[9];
    const float* We1 = (const float*)d_in[10]; const float* be1 = (const float*)d_in[11];
    const float* We2 = (const float*)d_in[12]; const float* be2 = (const float*)d_in[13];
    const float* Wa1 = (const float*)d_in[14]; const float* ba1 = (const float*)d_in[15];
    const float* Wa2 = (const float*)d_in[16]; const float* ba2 = (const float*)d_in[17];
    const float* Wm1 = (const float*)d_in[18]; const float* bm1 = (const float*)d_in[19];
    const float* Wm2 = (const float*)d_in[20]; const float* bm2 = (const float*)d_in[21];

    int N = in_sizes[0] / D;
    int E = in_sizes[3];

    float* ws = (float*)d_ws;
    size_t off = 0;
    auto alloc = [&](size_t n) { float* p = ws + off; off += (n + 63) & ~(size_t)63; return p; };

    float* Wqa = alloc(D * D); float* Wka = alloc(D * D); float* Wva = alloc(D * D);
    float* bqa = alloc(D);     float* bka = alloc(D);     float* bva = alloc(D);
    float* bounds = alloc(130);
    float* Aa = alloc(129 * D); float* Ba = alloc(129 * D);
    float* Am = alloc(129 * D); float* Bm = alloc(129 * D);
    float* qa = alloc((size_t)N * D);
    float* ka = alloc((size_t)N * D);
    float* va = alloc((size_t)N * D);
    float* S  = qa;  // alias: qa dead after edge_logits
    float* logits = alloc(E);
    float* exv    = alloc(E);
    unsigned* segmax = (unsigned*)alloc(N);
    float* segsum = alloc(N);

    hipMemsetAsync(segmax, 0, (size_t)N * 4, stream);  // 0 == ordered(-inf) floor
    hipMemsetAsync(segsum, 0, (size_t)N * 4, stream);

    prep_weights<<<387, 128, 0, stream>>>(Wq, bq, Wk, bk, Wv, bv, Wa1, ba1, Wm1, bm1,
                                          Wqa, Wka, Wva, bqa, bka, bva);
    prep_bounds<<<1, 128, 0, stream>>>(We1, be1, bounds);
    prep_tables<<<129, 128, 0, stream>>>(We1, be1, We2, be2, Wa1, Wm1, bounds, Aa, Ba, Am, Bm);

    node_gemm<<<(N + RPB - 1) / RPB, 256, 0, stream>>>(h, N, Wqa, Wka, Wva, bqa, bka, bva,
                                                       qa, ka, va);

    edge_logits<<<(E + 15) / 16, 256, 0, stream>>>(ei, eattr, E, qa, ka, Aa, Ba, Wa2, ba2,
                                                   bounds, logits, segmax);

    hipMemsetAsync(S, 0, (size_t)N * D * 4, stream);  // after edge_logits (S aliases qa)

    edge_expsum<<<(E + 255) / 256, 256, 0, stream>>>(ei, E, logits, segmax, exv, segsum);

    edge_msg<<<(E + 15) / 16, 256, 0, stream>>>(ei, eattr, E, va, Am, Bm, bounds, exv, segsum, S);

    node_out<<<(N + RPB - 1) / RPB, 256, 0, stream>>>(h, N, S, Wm2, bm2, segsum, (float*)d_out);

    copy_pos<<<(2 * N + 255) / 256, 256, 0, stream>>>(pos, 2 * N, (float*)d_out + (size_t)N * D);
}

// Round 2
// 636.735 us; speedup vs baseline: 3.8038x; 3.8038x over previous
//
#include <hip/hip_runtime.h>
#include <math.h>

#define D 128
#define RPB 32
#define SCAN_T 1024

// ---------------------------------------------------------------------------
// prep_weights: fold linear layers.
//   Wqa = Wq @ Wa1[0:128]     bqa = bq @ Wa1[0:128] + ba1
//   Wka = Wk @ Wa1[128:256]   bka = bk @ Wa1[128:256]
//   Wva = Wv @ Wm1[0:128]     bva = bv @ Wm1[0:128] + bm1
// ---------------------------------------------------------------------------
__global__ void prep_weights(const float* __restrict__ Wq, const float* __restrict__ bq,
                             const float* __restrict__ Wk, const float* __restrict__ bk,
                             const float* __restrict__ Wv, const float* __restrict__ bv,
                             const float* __restrict__ Wa1, const float* __restrict__ ba1,
                             const float* __restrict__ Wm1, const float* __restrict__ bm1,
                             float* __restrict__ Wqa, float* __restrict__ Wka, float* __restrict__ Wva,
                             float* __restrict__ bqa, float* __restrict__ bka, float* __restrict__ bva)
{
    int b = blockIdx.x;
    int j = threadIdx.x;
    if (b < 384) {
        int which = b >> 7, i = b & 127;
        const float *A, *B; float *C;
        if (which == 0)      { A = Wq; B = Wa1;           C = Wqa; }
        else if (which == 1) { A = Wk; B = Wa1 + 128 * D; C = Wka; }
        else                 { A = Wv; B = Wm1;           C = Wva; }
        float acc = 0.f;
        for (int k = 0; k < D; k++) acc += A[i * D + k] * B[k * D + j];
        C[i * D + j] = acc;
    } else {
        int which = b - 384;
        const float *bias, *B, *extra; float *out;
        if (which == 0)      { bias = bq; B = Wa1;           out = bqa; extra = ba1; }
        else if (which == 1) { bias = bk; B = Wa1 + 128 * D; out = bka; extra = nullptr; }
        else                 { bias = bv; B = Wm1;           out = bva; extra = bm1; }
        float acc = extra ? extra[j] : 0.f;
        for (int k = 0; k < D; k++) acc += bias[k] * B[k * D + j];
        out[j] = acc;
    }
}

// ---------------------------------------------------------------------------
// prep_bounds: sorted ReLU breakpoints of e(a), clipped to [0,1].
// ---------------------------------------------------------------------------
__global__ void prep_bounds(const float* __restrict__ We1, const float* __restrict__ be1,
                            float* __restrict__ bounds)
{
    __shared__ float sb[128];
    int j = threadIdx.x;
    float w = We1[j], b = be1[j];
    float t = (w != 0.f) ? (-b / w) : 2.f;
    t = fminf(fmaxf(t, 0.f), 1.f);
    sb[j] = t;
    __syncthreads();
    for (int k = 2; k <= 128; k <<= 1)
        for (int jj = k >> 1; jj > 0; jj >>= 1) {
            int ixj = j ^ jj;
            if (ixj > j) {
                float a = sb[j], c = sb[ixj];
                bool up = ((j & k) == 0);
                if (up ? (a > c) : (a < c)) { sb[j] = c; sb[ixj] = a; }
            }
            __syncthreads();
        }
    if (j == 0) { bounds[0] = 0.f; bounds[129] = 1.f; }
    bounds[1 + j] = sb[j];
}

// ---------------------------------------------------------------------------
// prep_tables: per interval, e(a)=a*Ae+Be projected through Wa1_e / Wm1_e.
// ---------------------------------------------------------------------------
__global__ void prep_tables(const float* __restrict__ We1, const float* __restrict__ be1,
                            const float* __restrict__ We2, const float* __restrict__ be2,
                            const float* __restrict__ Wa1, const float* __restrict__ Wm1,
                            const float* __restrict__ bounds,
                            float* __restrict__ Aa, float* __restrict__ Ba,
                            float* __restrict__ Am, float* __restrict__ Bm)
{
    int i = blockIdx.x;
    int j = threadIdx.x;
    __shared__ float Ae[128], Be[128];
    float m = 0.5f * (bounds[i] + bounds[i + 1]);
    float ae = 0.f, be = 0.f;
    for (int k = 0; k < 128; k++) {
        float w = We1[k], b = be1[k];
        if (m * w + b > 0.f) { ae += w * We2[k * D + j]; be += b * We2[k * D + j]; }
    }
    be += be2[j];
    Ae[j] = ae; Be[j] = be;
    __syncthreads();
    float aa = 0.f, ba = 0.f, am = 0.f, bm = 0.f;
    for (int l = 0; l < 128; l++) {
        float ael = Ae[l], bel = Be[l];
        float wa = Wa1[(256 + l) * D + j];
        float wm = Wm1[(128 + l) * D + j];
        aa += ael * wa; ba += bel * wa;
        am += ael * wm; bm += bel * wm;
    }
    Aa[i * D + j] = aa; Ba[i * D + j] = ba;
    Am[i * D + j] = am; Bm[i * D + j] = bm;
}

// ---------------------------------------------------------------------------
// node_gemm: qa/ka/va = h @ {Wqa,Wka,Wva} + bias.
// ---------------------------------------------------------------------------
__global__ __launch_bounds__(256) void node_gemm(
    const float* __restrict__ h, int N,
    const float* __restrict__ Wqa, const float* __restrict__ Wka, const float* __restrict__ Wva,
    const float* __restrict__ bqa, const float* __restrict__ bka, const float* __restrict__ bva,
    float* __restrict__ qa, float* __restrict__ ka, float* __restrict__ va)
{
    __shared__ float hs[RPB][D];
    int r0 = blockIdx.x * RPB;
    int t = threadIdx.x;
    for (int x = t; x < RPB * D; x += 256) {
        int r = x >> 7, cc = x & 127;
        hs[r][cc] = (r0 + r < N) ? h[(size_t)(r0 + r) * D + cc] : 0.f;
    }
    __syncthreads();
    int c = t & 127;
    int half = t >> 7;
    float acc0[16], acc1[16], acc2[16];
#pragma unroll
    for (int r = 0; r < 16; r++) { acc0[r] = 0.f; acc1[r] = 0.f; acc2[r] = 0.f; }
    for (int k = 0; k < D; k++) {
        float w0 = Wqa[k * D + c], w1 = Wka[k * D + c], w2 = Wva[k * D + c];
#pragma unroll
        for (int r = 0; r < 16; r++) {
            float hv = hs[half * 16 + r][k];
            acc0[r] += hv * w0; acc1[r] += hv * w1; acc2[r] += hv * w2;
        }
    }
    float b0 = bqa[c], b1 = bka[c], b2 = bva[c];
#pragma unroll
    for (int r = 0; r < 16; r++) {
        int row = r0 + half * 16 + r;
        if (row < N) {
            qa[(size_t)row * D + c] = acc0[r] + b0;
            ka[(size_t)row * D + c] = acc1[r] + b1;
            va[(size_t)row * D + c] = acc2[r] + b2;
        }
    }
}

// ---------------------------------------------------------------------------
// CSR build: histogram -> scan -> scatter
// ---------------------------------------------------------------------------
__global__ __launch_bounds__(256) void k_hist(const int* __restrict__ ei, int E,
                                              int* __restrict__ deg)
{
    int e = blockIdx.x * 256 + threadIdx.x;
    if (e < E) atomicAdd(deg + ei[E + e], 1);
}

__global__ __launch_bounds__(SCAN_T) void k_scan(const int* __restrict__ deg, int N,
                                                 int* __restrict__ off, int* __restrict__ cur)
{
    __shared__ int ls[SCAN_T];
    int t = threadIdx.x;
    int chunk = (N + SCAN_T - 1) / SCAN_T;
    int s0 = t * chunk, s1 = min(s0 + chunk, N);
    int sum = 0;
    for (int i = s0; i < s1; i++) sum += deg[i];
    ls[t] = sum;
    __syncthreads();
    int val = sum;
    for (int sft = 1; sft < SCAN_T; sft <<= 1) {
        int add = (t >= sft) ? ls[t - sft] : 0;
        __syncthreads();
        val += add;
        ls[t] = val;
        __syncthreads();
    }
    int run = val - sum;  // exclusive prefix for this thread's chunk
    for (int i = s0; i < s1; i++) {
        off[i] = run; cur[i] = run;
        run += deg[i];
    }
    if (t == SCAN_T - 1) off[N] = val;
}

__global__ __launch_bounds__(256) void k_scatter(const int* __restrict__ ei, int E,
                                                 int* __restrict__ cur, int* __restrict__ eids)
{
    int e = blockIdx.x * 256 + threadIdx.x;
    if (e < E) {
        int c = ei[E + e];
        int p = atomicAdd(cur + c, 1);
        eids[p] = e;
    }
}

// ---------------------------------------------------------------------------
// edge_logits: 16 lanes/edge. logit = relu(qa[col]+ka[row]+a*Aa+Ba).Wa2+ba2
// ---------------------------------------------------------------------------
__global__ __launch_bounds__(256) void edge_logits(
    const int* __restrict__ ei, const float* __restrict__ eattr, int E,
    const float* __restrict__ qa, const float* __restrict__ ka,
    const float* __restrict__ Aa, const float* __restrict__ Ba,
    const float* __restrict__ Wa2, const float* __restrict__ ba2,
    const float* __restrict__ bounds,
    float* __restrict__ logits)
{
    __shared__ float b[130];
    int t = threadIdx.x;
    if (t < 130) b[t] = bounds[t];
    __syncthreads();
    int g = t >> 4, l = t & 15;
    int e = blockIdx.x * 16 + g;
    if (e >= E) return;
    int row = ei[e], col = ei[E + e];
    float a = eattr[e];
    int lo = 0, hi = 128;
    while (lo < hi) { int mid = (lo + hi + 1) >> 1; if (b[mid] <= a) lo = mid; else hi = mid - 1; }
    int i = lo;
    int d = l * 8;
    const float4* q4 = (const float4*)(qa + (size_t)col * D + d);
    const float4* k4 = (const float4*)(ka + (size_t)row * D + d);
    const float4* A4 = (const float4*)(Aa + i * D + d);
    const float4* B4 = (const float4*)(Ba + i * D + d);
    const float4* w4 = (const float4*)(Wa2 + d);
    float part = 0.f;
#pragma unroll
    for (int p = 0; p < 2; p++) {
        float4 qv = q4[p], kv = k4[p], Av = A4[p], Bv = B4[p], wv = w4[p];
        part += fmaxf(qv.x + kv.x + a * Av.x + Bv.x, 0.f) * wv.x;
        part += fmaxf(qv.y + kv.y + a * Av.y + Bv.y, 0.f) * wv.y;
        part += fmaxf(qv.z + kv.z + a * Av.z + Bv.z, 0.f) * wv.z;
        part += fmaxf(qv.w + kv.w + a * Av.w + Bv.w, 0.f) * wv.w;
    }
#pragma unroll
    for (int s = 1; s < 16; s <<= 1) part += __shfl_xor(part, s, 64);
    if (l == 0) logits[e] = part + ba2[0];
}

// ---------------------------------------------------------------------------
// node_msg: one wave per destination node. pass1: m = max(logits of my edges).
// pass2: gather va[row], hid = silu(va+a*Am+Bm); acc += exp(logit-m)*hid.
// S[n] = acc/(ssum+1e-16); segsum[n] = ssum. No atomics anywhere.
// ---------------------------------------------------------------------------
__global__ __launch_bounds__(256) void node_msg(
    const int* __restrict__ ei, const float* __restrict__ eattr, int E, int N,
    const int* __restrict__ off, const int* __restrict__ eids,
    const float* __restrict__ va, const float* __restrict__ Am, const float* __restrict__ Bm,
    const float* __restrict__ bounds, const float* __restrict__ logits,
    float* __restrict__ S, float* __restrict__ segsum)
{
    __shared__ float b[130];
    int t = threadIdx.x;
    if (t < 130) b[t] = bounds[t];
    __syncthreads();
    int lane = t & 63, wv = t >> 6;
    int n = blockIdx.x * 4 + wv;
    if (n >= N) return;
    int start = off[n], end = off[n + 1];
    float m = -INFINITY;
    for (int idx = start; idx < end; idx++)
        m = fmaxf(m, logits[eids[idx]]);
    float acc0 = 0.f, acc1 = 0.f, ssum = 0.f;
    for (int idx = start; idx < end; idx++) {
        int e = eids[idx];
        int row = ei[e];
        float a = eattr[e];
        int lo = 0, hi = 128;
        while (lo < hi) { int mid = (lo + hi + 1) >> 1; if (b[mid] <= a) lo = mid; else hi = mid - 1; }
        int i = lo;
        float ex = expf(logits[e] - m);
        float x0 = va[(size_t)row * D + lane]      + a * Am[i * D + lane]      + Bm[i * D + lane];
        float x1 = va[(size_t)row * D + 64 + lane] + a * Am[i * D + 64 + lane] + Bm[i * D + 64 + lane];
        float s0 = x0 / (1.f + expf(-x0));
        float s1 = x1 / (1.f + expf(-x1));
        acc0 += ex * s0;
        acc1 += ex * s1;
        ssum += ex;
    }
    float inv = 1.f / (ssum + 1e-16f);
    S[(size_t)n * D + lane]      = acc0 * inv;
    S[(size_t)n * D + 64 + lane] = acc1 * inv;
    if (lane == 0) segsum[n] = ssum;
}

// ---------------------------------------------------------------------------
// node_out: out = h + S@Wm2 + bm2 * (segsum/(segsum+1e-16))
// ---------------------------------------------------------------------------
__global__ __launch_bounds__(256) void node_out(
    const float* __restrict__ h, int N,
    const float* __restrict__ S, const float* __restrict__ Wm2, const float* __restrict__ bm2,
    const float* __restrict__ segsum, float* __restrict__ out)
{
    __shared__ float Ss[RPB][D];
    int r0 = blockIdx.x * RPB;
    int t = threadIdx.x;
    for (int x = t; x < RPB * D; x += 256) {
        int r = x >> 7, cc = x & 127;
        Ss[r][cc] = (r0 + r < N) ? S[(size_t)(r0 + r) * D + cc] : 0.f;
    }
    __syncthreads();
    int c = t & 127, half = t >> 7;
    float acc[16];
#pragma unroll
    for (int r = 0; r < 16; r++) acc[r] = 0.f;
    for (int k = 0; k < D; k++) {
        float w = Wm2[k * D + c];
#pragma unroll
        for (int r = 0; r < 16; r++) acc[r] += Ss[half * 16 + r][k] * w;
    }
    float bb = bm2[c];
#pragma unroll
    for (int r = 0; r < 16; r++) {
        int row = r0 + half * 16 + r;
        if (row < N) {
            float ws = segsum[row];
            ws = ws / (ws + 1e-16f);
            out[(size_t)row * D + c] = h[(size_t)row * D + c] + acc[r] + bb * ws;
        }
    }
}

__global__ void copy_pos(const float* __restrict__ pos, int n, float* __restrict__ out)
{
    int i = blockIdx.x * 256 + threadIdx.x;
    if (i < n) out[i] = pos[i];
}

extern "C" void kernel_launch(void* const* d_in, const int* in_sizes, int n_in,
                              void* d_out, int out_size, void* d_ws, size_t ws_size,
                              hipStream_t stream)
{
    const float* h     = (const float*)d_in[0];
    const float* pos   = (const float*)d_in[1];
    const int*   ei    = (const int*)d_in[2];
    const float* eattr = (const float*)d_in[3];
    const float* Wq  = (const float*)d_in[4];  const float* bq  = (const float*)d_in[5];
    const float* Wk  = (const float*)d_in[6];  const float* bk  = (const float*)d_in[7];
    const float* Wv  = (const float*)d_in[8];  const float* bv  = (const float*)d_in[9];
    const float* We1 = (const float*)d_in[10]; const float* be1 = (const float*)d_in[11];
    const float* We2 = (const float*)d_in[12]; const float* be2 = (const float*)d_in[13];
    const float* Wa1 = (const float*)d_in[14]; const float* ba1 = (const float*)d_in[15];
    const float* Wa2 = (const float*)d_in[16]; const float* ba2 = (const float*)d_in[17];
    const float* Wm1 = (const float*)d_in[18]; const float* bm1 = (const float*)d_in[19];
    const float* Wm2 = (const float*)d_in[20]; const float* bm2 = (const float*)d_in[21];

    int N = in_sizes[0] / D;
    int E = in_sizes[3];

    float* ws = (float*)d_ws;
    size_t off_f = 0;
    auto alloc = [&](size_t n) { float* p = ws + off_f; off_f += (n + 63) & ~(size_t)63; return p; };

    float* Wqa = alloc(D * D); float* Wka = alloc(D * D); float* Wva = alloc(D * D);
    float* bqa = alloc(D);     float* bka = alloc(D);     float* bva = alloc(D);
    float* bounds = alloc(130);
    float* Aa = alloc(129 * D); float* Ba = alloc(129 * D);
    float* Am = alloc(129 * D); float* Bm = alloc(129 * D);
    float* qa = alloc((size_t)N * D);
    float* ka = alloc((size_t)N * D);
    float* va = alloc((size_t)N * D);
    float* S  = qa;  // alias: qa dead after edge_logits
    float* logits = alloc(E);
    float* segsum = alloc(N);
    int* deg  = (int*)alloc(N);
    int* offs = (int*)alloc(N + 1);
    int* cur  = (int*)alloc(N);
    int* eids = (int*)alloc(E);

    hipMemsetAsync(deg, 0, (size_t)N * 4, stream);

    prep_weights<<<387, 128, 0, stream>>>(Wq, bq, Wk, bk, Wv, bv, Wa1, ba1, Wm1, bm1,
                                          Wqa, Wka, Wva, bqa, bka, bva);
    prep_bounds<<<1, 128, 0, stream>>>(We1, be1, bounds);
    prep_tables<<<129, 128, 0, stream>>>(We1, be1, We2, be2, Wa1, Wm1, bounds, Aa, Ba, Am, Bm);

    // CSR build (independent of node_gemm; cheap int atomics only)
    k_hist<<<(E + 255) / 256, 256, 0, stream>>>(ei, E, deg);
    k_scan<<<1, SCAN_T, 0, stream>>>(deg, N, offs, cur);
    k_scatter<<<(E + 255) / 256, 256, 0, stream>>>(ei, E, cur, eids);

    node_gemm<<<(N + RPB - 1) / RPB, 256, 0, stream>>>(h, N, Wqa, Wka, Wva, bqa, bka, bva,
                                                       qa, ka, va);

    edge_logits<<<(E + 15) / 16, 256, 0, stream>>>(ei, eattr, E, qa, ka, Aa, Ba, Wa2, ba2,
                                                   bounds, logits);

    node_msg<<<(N + 3) / 4, 256, 0, stream>>>(ei, eattr, E, N, offs, eids, va, Am, Bm,
                                              bounds, logits, S, segsum);

    node_out<<<(N + RPB - 1) / RPB, 256, 0, stream>>>(h, N, S, Wm2, bm2, segsum, (float*)d_out);

    copy_pos<<<(2 * N + 255) / 256, 256, 0, stream>>>(pos, 2 * N, (float*)d_out + (size_t)N * D);
}

// Round 3
// 532.082 us; speedup vs baseline: 4.5520x; 1.1967x over previous
//
#include <hip/hip_runtime.h>
#include <math.h>

#define D 128
#define RPB 32
#define SCAN_T 1024
#define CAP 128

// ---------------------------------------------------------------------------
// prep_weights: fold linear layers.
//   Wqa = Wq @ Wa1[0:128]     bqa = bq @ Wa1[0:128] + ba1
//   Wka = Wk @ Wa1[128:256]   bka = bk @ Wa1[128:256]
//   Wva = Wv @ Wm1[0:128]     bva = bv @ Wm1[0:128] + bm1
// ---------------------------------------------------------------------------
__global__ void prep_weights(const float* __restrict__ Wq, const float* __restrict__ bq,
                             const float* __restrict__ Wk, const float* __restrict__ bk,
                             const float* __restrict__ Wv, const float* __restrict__ bv,
                             const float* __restrict__ Wa1, const float* __restrict__ ba1,
                             const float* __restrict__ Wm1, const float* __restrict__ bm1,
                             float* __restrict__ Wqa, float* __restrict__ Wka, float* __restrict__ Wva,
                             float* __restrict__ bqa, float* __restrict__ bka, float* __restrict__ bva)
{
    int b = blockIdx.x;
    int j = threadIdx.x;
    if (b < 384) {
        int which = b >> 7, i = b & 127;
        const float *A, *B; float *C;
        if (which == 0)      { A = Wq; B = Wa1;           C = Wqa; }
        else if (which == 1) { A = Wk; B = Wa1 + 128 * D; C = Wka; }
        else                 { A = Wv; B = Wm1;           C = Wva; }
        float acc = 0.f;
        for (int k = 0; k < D; k++) acc += A[i * D + k] * B[k * D + j];
        C[i * D + j] = acc;
    } else {
        int which = b - 384;
        const float *bias, *B, *extra; float *out;
        if (which == 0)      { bias = bq; B = Wa1;           out = bqa; extra = ba1; }
        else if (which == 1) { bias = bk; B = Wa1 + 128 * D; out = bka; extra = nullptr; }
        else                 { bias = bv; B = Wm1;           out = bva; extra = bm1; }
        float acc = extra ? extra[j] : 0.f;
        for (int k = 0; k < D; k++) acc += bias[k] * B[k * D + j];
        out[j] = acc;
    }
}

// ---------------------------------------------------------------------------
// prep_bounds: sorted ReLU breakpoints of e(a), clipped to [0,1].
// ---------------------------------------------------------------------------
__global__ void prep_bounds(const float* __restrict__ We1, const float* __restrict__ be1,
                            float* __restrict__ bounds)
{
    __shared__ float sb[128];
    int j = threadIdx.x;
    float w = We1[j], b = be1[j];
    float t = (w != 0.f) ? (-b / w) : 2.f;
    t = fminf(fmaxf(t, 0.f), 1.f);
    sb[j] = t;
    __syncthreads();
    for (int k = 2; k <= 128; k <<= 1)
        for (int jj = k >> 1; jj > 0; jj >>= 1) {
            int ixj = j ^ jj;
            if (ixj > j) {
                float a = sb[j], c = sb[ixj];
                bool up = ((j & k) == 0);
                if (up ? (a > c) : (a < c)) { sb[j] = c; sb[ixj] = a; }
            }
            __syncthreads();
        }
    if (j == 0) { bounds[0] = 0.f; bounds[129] = 1.f; }
    bounds[1 + j] = sb[j];
}

// ---------------------------------------------------------------------------
// prep_tables: per interval, e(a)=a*Ae+Be projected through Wa1_e / Wm1_e.
// ---------------------------------------------------------------------------
__global__ void prep_tables(const float* __restrict__ We1, const float* __restrict__ be1,
                            const float* __restrict__ We2, const float* __restrict__ be2,
                            const float* __restrict__ Wa1, const float* __restrict__ Wm1,
                            const float* __restrict__ bounds,
                            float* __restrict__ Aa, float* __restrict__ Ba,
                            float* __restrict__ Am, float* __restrict__ Bm)
{
    int i = blockIdx.x;
    int j = threadIdx.x;
    __shared__ float Ae[128], Be[128];
    float m = 0.5f * (bounds[i] + bounds[i + 1]);
    float ae = 0.f, be = 0.f;
    for (int k = 0; k < 128; k++) {
        float w = We1[k], b = be1[k];
        if (m * w + b > 0.f) { ae += w * We2[k * D + j]; be += b * We2[k * D + j]; }
    }
    be += be2[j];
    Ae[j] = ae; Be[j] = be;
    __syncthreads();
    float aa = 0.f, ba = 0.f, am = 0.f, bm = 0.f;
    for (int l = 0; l < 128; l++) {
        float ael = Ae[l], bel = Be[l];
        float wa = Wa1[(256 + l) * D + j];
        float wm = Wm1[(128 + l) * D + j];
        aa += ael * wa; ba += bel * wa;
        am += ael * wm; bm += bel * wm;
    }
    Aa[i * D + j] = aa; Ba[i * D + j] = ba;
    Am[i * D + j] = am; Bm[i * D + j] = bm;
}

// ---------------------------------------------------------------------------
// node_gemm: qa/ka/va = h @ {Wqa,Wka,Wva} + bias.
// ---------------------------------------------------------------------------
__global__ __launch_bounds__(256) void node_gemm(
    const float* __restrict__ h, int N,
    const float* __restrict__ Wqa, const float* __restrict__ Wka, const float* __restrict__ Wva,
    const float* __restrict__ bqa, const float* __restrict__ bka, const float* __restrict__ bva,
    float* __restrict__ qa, float* __restrict__ ka, float* __restrict__ va)
{
    __shared__ float hs[RPB][D];
    int r0 = blockIdx.x * RPB;
    int t = threadIdx.x;
    for (int x = t; x < RPB * D; x += 256) {
        int r = x >> 7, cc = x & 127;
        hs[r][cc] = (r0 + r < N) ? h[(size_t)(r0 + r) * D + cc] : 0.f;
    }
    __syncthreads();
    int c = t & 127;
    int half = t >> 7;
    float acc0[16], acc1[16], acc2[16];
#pragma unroll
    for (int r = 0; r < 16; r++) { acc0[r] = 0.f; acc1[r] = 0.f; acc2[r] = 0.f; }
    for (int k = 0; k < D; k++) {
        float w0 = Wqa[k * D + c], w1 = Wka[k * D + c], w2 = Wva[k * D + c];
#pragma unroll
        for (int r = 0; r < 16; r++) {
            float hv = hs[half * 16 + r][k];
            acc0[r] += hv * w0; acc1[r] += hv * w1; acc2[r] += hv * w2;
        }
    }
    float b0 = bqa[c], b1 = bka[c], b2 = bva[c];
#pragma unroll
    for (int r = 0; r < 16; r++) {
        int row = r0 + half * 16 + r;
        if (row < N) {
            qa[(size_t)row * D + c] = acc0[r] + b0;
            ka[(size_t)row * D + c] = acc1[r] + b1;
            va[(size_t)row * D + c] = acc2[r] + b2;
        }
    }
}

// ---------------------------------------------------------------------------
// CSR build: histogram -> scan -> scatter(with packed records + interval idx)
// ---------------------------------------------------------------------------
__global__ __launch_bounds__(256) void k_hist(const int* __restrict__ ei, int E,
                                              int* __restrict__ deg)
{
    int e = blockIdx.x * 256 + threadIdx.x;
    if (e < E) atomicAdd(deg + ei[E + e], 1);
}

__global__ __launch_bounds__(SCAN_T) void k_scan(const int* __restrict__ deg, int N,
                                                 int* __restrict__ off, int* __restrict__ cur)
{
    __shared__ int ls[SCAN_T];
    int t = threadIdx.x;
    int chunk = (N + SCAN_T - 1) / SCAN_T;
    int s0 = t * chunk, s1 = min(s0 + chunk, N);
    int sum = 0;
    for (int i = s0; i < s1; i++) sum += deg[i];
    ls[t] = sum;
    __syncthreads();
    int val = sum;
    for (int sft = 1; sft < SCAN_T; sft <<= 1) {
        int add = (t >= sft) ? ls[t - sft] : 0;
        __syncthreads();
        val += add;
        ls[t] = val;
        __syncthreads();
    }
    int run = val - sum;
    for (int i = s0; i < s1; i++) {
        off[i] = run; cur[i] = run;
        run += deg[i];
    }
    if (t == SCAN_T - 1) off[N] = val;
}

// scatter packed records {row, bits(a), interval} into CSR slots
__global__ __launch_bounds__(256) void k_scatter(const int* __restrict__ ei,
                                                 const float* __restrict__ eattr, int E,
                                                 const float* __restrict__ bounds,
                                                 int* __restrict__ cur, int4* __restrict__ recs)
{
    __shared__ float b[130];
    int t = threadIdx.x;
    if (t < 130) b[t] = bounds[t];
    __syncthreads();
    int e = blockIdx.x * 256 + t;
    if (e >= E) return;
    int row = ei[e], col = ei[E + e];
    float a = eattr[e];
    int lo = 0, hi = 128;
    while (lo < hi) { int mid = (lo + hi + 1) >> 1; if (b[mid] <= a) lo = mid; else hi = mid - 1; }
    int p = atomicAdd(cur + col, 1);
    recs[p] = make_int4(row, __float_as_int(a), lo, 0);
}

// ---------------------------------------------------------------------------
// node_all: one wave per destination node; fused logits + online softmax +
// silu message aggregation. qa[n], Wa2 hoisted to registers. Logits parked in
// per-wave LDS per CAP-chunk; online rescale across chunks handles any degree.
// No atomics, no logits round-trip.
// ---------------------------------------------------------------------------
__global__ __launch_bounds__(256) void node_all(
    const int4* __restrict__ recs, int N,
    const int* __restrict__ off,
    const float* __restrict__ qa, const float* __restrict__ ka, const float* __restrict__ va,
    const float* __restrict__ Aa, const float* __restrict__ Ba,
    const float* __restrict__ Am, const float* __restrict__ Bm,
    const float* __restrict__ Wa2, const float* __restrict__ ba2,
    float* __restrict__ S, float* __restrict__ segsum)
{
    __shared__ float lgl[4][CAP];
    int t = threadIdx.x;
    int lane = t & 63, wv = t >> 6;
    int n = blockIdx.x * 4 + wv;
    if (n >= N) return;

    float q0 = qa[(size_t)n * D + lane];
    float q1 = qa[(size_t)n * D + 64 + lane];
    float w0 = Wa2[lane], w1 = Wa2[64 + lane];
    float ba2v = ba2[0];

    int start = off[n], end = off[n + 1];
    float m_run = -INFINITY, acc0 = 0.f, acc1 = 0.f, ssum = 0.f;

    for (int cb = start; cb < end; cb += CAP) {
        int ce = min(cb + CAP, end);
        float mc = -INFINITY;
        // pass 1: logits for this chunk
        for (int idx = cb; idx < ce; idx++) {
            int4 rec = recs[idx];
            int row = rec.x; float a = __int_as_float(rec.y); int i = rec.z;
            size_t rb = (size_t)row * D;
            int ib = i * D;
            float t0 = fmaxf(q0 + ka[rb + lane]      + a * Aa[ib + lane]      + Ba[ib + lane],      0.f) * w0;
            float t1 = fmaxf(q1 + ka[rb + 64 + lane] + a * Aa[ib + 64 + lane] + Ba[ib + 64 + lane], 0.f) * w1;
            float part = t0 + t1;
#pragma unroll
            for (int s2 = 1; s2 < 64; s2 <<= 1) part += __shfl_xor(part, s2, 64);
            float lg = part + ba2v;
            mc = fmaxf(mc, lg);
            if (lane == 0) lgl[wv][idx - cb] = lg;
        }
        float m_new = fmaxf(m_run, mc);
        float sc = __expf(m_run - m_new);   // exp(-inf)=0 on first chunk
        acc0 *= sc; acc1 *= sc; ssum *= sc;
        // pass 2: weighted silu messages
        for (int idx = cb; idx < ce; idx++) {
            int4 rec = recs[idx];
            int row = rec.x; float a = __int_as_float(rec.y); int i = rec.z;
            size_t rb = (size_t)row * D;
            int ib = i * D;
            float ex = __expf(lgl[wv][idx - cb] - m_new);
            float x0 = va[rb + lane]      + a * Am[ib + lane]      + Bm[ib + lane];
            float x1 = va[rb + 64 + lane] + a * Am[ib + 64 + lane] + Bm[ib + 64 + lane];
            float s0 = x0 * __builtin_amdgcn_rcpf(1.f + __expf(-x0));
            float s1 = x1 * __builtin_amdgcn_rcpf(1.f + __expf(-x1));
            acc0 += ex * s0; acc1 += ex * s1; ssum += ex;
        }
        m_run = m_new;
    }

    float inv = __builtin_amdgcn_rcpf(ssum + 1e-16f);
    S[(size_t)n * D + lane]      = acc0 * inv;
    S[(size_t)n * D + 64 + lane] = acc1 * inv;
    if (lane == 0) segsum[n] = ssum;
}

// ---------------------------------------------------------------------------
// node_out: out = h + S@Wm2 + bm2 * (segsum/(segsum+1e-16))
// ---------------------------------------------------------------------------
__global__ __launch_bounds__(256) void node_out(
    const float* __restrict__ h, int N,
    const float* __restrict__ S, const float* __restrict__ Wm2, const float* __restrict__ bm2,
    const float* __restrict__ segsum, float* __restrict__ out)
{
    __shared__ float Ss[RPB][D];
    int r0 = blockIdx.x * RPB;
    int t = threadIdx.x;
    for (int x = t; x < RPB * D; x += 256) {
        int r = x >> 7, cc = x & 127;
        Ss[r][cc] = (r0 + r < N) ? S[(size_t)(r0 + r) * D + cc] : 0.f;
    }
    __syncthreads();
    int c = t & 127, half = t >> 7;
    float acc[16];
#pragma unroll
    for (int r = 0; r < 16; r++) acc[r] = 0.f;
    for (int k = 0; k < D; k++) {
        float w = Wm2[k * D + c];
#pragma unroll
        for (int r = 0; r < 16; r++) acc[r] += Ss[half * 16 + r][k] * w;
    }
    float bb = bm2[c];
#pragma unroll
    for (int r = 0; r < 16; r++) {
        int row = r0 + half * 16 + r;
        if (row < N) {
            float ws = segsum[row];
            ws = ws / (ws + 1e-16f);
            out[(size_t)row * D + c] = h[(size_t)row * D + c] + acc[r] + bb * ws;
        }
    }
}

__global__ void copy_pos(const float* __restrict__ pos, int n, float* __restrict__ out)
{
    int i = blockIdx.x * 256 + threadIdx.x;
    if (i < n) out[i] = pos[i];
}

extern "C" void kernel_launch(void* const* d_in, const int* in_sizes, int n_in,
                              void* d_out, int out_size, void* d_ws, size_t ws_size,
                              hipStream_t stream)
{
    const float* h     = (const float*)d_in[0];
    const float* pos   = (const float*)d_in[1];
    const int*   ei    = (const int*)d_in[2];
    const float* eattr = (const float*)d_in[3];
    const float* Wq  = (const float*)d_in[4];  const float* bq  = (const float*)d_in[5];
    const float* Wk  = (const float*)d_in[6];  const float* bk  = (const float*)d_in[7];
    const float* Wv  = (const float*)d_in[8];  const float* bv  = (const float*)d_in[9];
    const float* We1 = (const float*)d_in[10]; const float* be1 = (const float*)d_in[11];
    const float* We2 = (const float*)d_in[12]; const float* be2 = (const float*)d_in[13];
    const float* Wa1 = (const float*)d_in[14]; const float* ba1 = (const float*)d_in[15];
    const float* Wa2 = (const float*)d_in[16]; const float* ba2 = (const float*)d_in[17];
    const float* Wm1 = (const float*)d_in[18]; const float* bm1 = (const float*)d_in[19];
    const float* Wm2 = (const float*)d_in[20]; const float* bm2 = (const float*)d_in[21];

    int N = in_sizes[0] / D;
    int E = in_sizes[3];

    float* ws = (float*)d_ws;
    size_t off_f = 0;
    auto alloc = [&](size_t n) { float* p = ws + off_f; off_f += (n + 63) & ~(size_t)63; return p; };

    float* Wqa = alloc(D * D); float* Wka = alloc(D * D); float* Wva = alloc(D * D);
    float* bqa = alloc(D);     float* bka = alloc(D);     float* bva = alloc(D);
    float* bounds = alloc(130);
    float* Aa = alloc(129 * D); float* Ba = alloc(129 * D);
    float* Am = alloc(129 * D); float* Bm = alloc(129 * D);
    float* qa = alloc((size_t)N * D);
    float* ka = alloc((size_t)N * D);
    float* va = alloc((size_t)N * D);
    float* S  = qa;  // alias: wave n reads qa row n before writing S row n; no cross-row use
    float* segsum = alloc(N);
    int* deg  = (int*)alloc(N);
    int* offs = (int*)alloc(N + 1);
    int* cur  = (int*)alloc(N);
    int4* recs = (int4*)alloc((size_t)E * 4);

    hipMemsetAsync(deg, 0, (size_t)N * 4, stream);

    prep_weights<<<387, 128, 0, stream>>>(Wq, bq, Wk, bk, Wv, bv, Wa1, ba1, Wm1, bm1,
                                          Wqa, Wka, Wva, bqa, bka, bva);
    prep_bounds<<<1, 128, 0, stream>>>(We1, be1, bounds);
    prep_tables<<<129, 128, 0, stream>>>(We1, be1, We2, be2, Wa1, Wm1, bounds, Aa, Ba, Am, Bm);

    // CSR build with packed records (needs bounds for interval index)
    k_hist<<<(E + 255) / 256, 256, 0, stream>>>(ei, E, deg);
    k_scan<<<1, SCAN_T, 0, stream>>>(deg, N, offs, cur);
    k_scatter<<<(E + 255) / 256, 256, 0, stream>>>(ei, eattr, E, bounds, cur, recs);

    node_gemm<<<(N + RPB - 1) / RPB, 256, 0, stream>>>(h, N, Wqa, Wka, Wva, bqa, bka, bva,
                                                       qa, ka, va);

    node_all<<<(N + 3) / 4, 256, 0, stream>>>(recs, N, offs, qa, ka, va, Aa, Ba, Am, Bm,
                                              Wa2, ba2, S, segsum);

    node_out<<<(N + RPB - 1) / RPB, 256, 0, stream>>>(h, N, S, Wm2, bm2, segsum, (float*)d_out);

    copy_pos<<<(2 * N + 255) / 256, 256, 0, stream>>>(pos, 2 * N, (float*)d_out + (size_t)N * D);
}

// Round 4
// 349.694 us; speedup vs baseline: 6.9262x; 1.5216x over previous
//
#include <hip/hip_runtime.h>
#include <math.h>

#define D 128
#define RPB 32
#define SB 256

// ---------------------------------------------------------------------------
// prep_weights: fold linear layers.
//   Wqa = Wq @ Wa1[0:128]     bqa = bq @ Wa1[0:128] + ba1
//   Wka = Wk @ Wa1[128:256]   bka = bk @ Wa1[128:256]
//   Wva = Wv @ Wm1[0:128]     bva = bv @ Wm1[0:128] + bm1
// ---------------------------------------------------------------------------
__global__ void prep_weights(const float* __restrict__ Wq, const float* __restrict__ bq,
                             const float* __restrict__ Wk, const float* __restrict__ bk,
                             const float* __restrict__ Wv, const float* __restrict__ bv,
                             const float* __restrict__ Wa1, const float* __restrict__ ba1,
                             const float* __restrict__ Wm1, const float* __restrict__ bm1,
                             float* __restrict__ Wqa, float* __restrict__ Wka, float* __restrict__ Wva,
                             float* __restrict__ bqa, float* __restrict__ bka, float* __restrict__ bva)
{
    int b = blockIdx.x;
    int j = threadIdx.x;
    if (b < 384) {
        int which = b >> 7, i = b & 127;
        const float *A, *B; float *C;
        if (which == 0)      { A = Wq; B = Wa1;           C = Wqa; }
        else if (which == 1) { A = Wk; B = Wa1 + 128 * D; C = Wka; }
        else                 { A = Wv; B = Wm1;           C = Wva; }
        float acc = 0.f;
        for (int k = 0; k < D; k++) acc += A[i * D + k] * B[k * D + j];
        C[i * D + j] = acc;
    } else {
        int which = b - 384;
        const float *bias, *B, *extra; float *out;
        if (which == 0)      { bias = bq; B = Wa1;           out = bqa; extra = ba1; }
        else if (which == 1) { bias = bk; B = Wa1 + 128 * D; out = bka; extra = nullptr; }
        else                 { bias = bv; B = Wm1;           out = bva; extra = bm1; }
        float acc = extra ? extra[j] : 0.f;
        for (int k = 0; k < D; k++) acc += bias[k] * B[k * D + j];
        out[j] = acc;
    }
}

// ---------------------------------------------------------------------------
// prep_bounds: sorted ReLU breakpoints of e(a), clipped to [0,1].
// ---------------------------------------------------------------------------
__global__ void prep_bounds(const float* __restrict__ We1, const float* __restrict__ be1,
                            float* __restrict__ bounds)
{
    __shared__ float sb[128];
    int j = threadIdx.x;
    float w = We1[j], b = be1[j];
    float t = (w != 0.f) ? (-b / w) : 2.f;
    t = fminf(fmaxf(t, 0.f), 1.f);
    sb[j] = t;
    __syncthreads();
    for (int k = 2; k <= 128; k <<= 1)
        for (int jj = k >> 1; jj > 0; jj >>= 1) {
            int ixj = j ^ jj;
            if (ixj > j) {
                float a = sb[j], c = sb[ixj];
                bool up = ((j & k) == 0);
                if (up ? (a > c) : (a < c)) { sb[j] = c; sb[ixj] = a; }
            }
            __syncthreads();
        }
    if (j == 0) { bounds[0] = 0.f; bounds[129] = 1.f; }
    bounds[1 + j] = sb[j];
}

// ---------------------------------------------------------------------------
// prep_tables: per interval, e(a)=a*Ae+Be projected through Wa1_e / Wm1_e.
// Output layout interleaved: AB[i*128+j] = {Aa,Ba}, MB[i*128+j] = {Am,Bm}.
// ---------------------------------------------------------------------------
__global__ void prep_tables(const float* __restrict__ We1, const float* __restrict__ be1,
                            const float* __restrict__ We2, const float* __restrict__ be2,
                            const float* __restrict__ Wa1, const float* __restrict__ Wm1,
                            const float* __restrict__ bounds,
                            float2* __restrict__ AB, float2* __restrict__ MB)
{
    int i = blockIdx.x;
    int j = threadIdx.x;
    __shared__ float Ae[128], Be[128];
    float m = 0.5f * (bounds[i] + bounds[i + 1]);
    float ae = 0.f, be = 0.f;
    for (int k = 0; k < 128; k++) {
        float w = We1[k], b = be1[k];
        if (m * w + b > 0.f) { ae += w * We2[k * D + j]; be += b * We2[k * D + j]; }
    }
    be += be2[j];
    Ae[j] = ae; Be[j] = be;
    __syncthreads();
    float aa = 0.f, ba = 0.f, am = 0.f, bm = 0.f;
    for (int l = 0; l < 128; l++) {
        float ael = Ae[l], bel = Be[l];
        float wa = Wa1[(256 + l) * D + j];
        float wm = Wm1[(128 + l) * D + j];
        aa += ael * wa; ba += bel * wa;
        am += ael * wm; bm += bel * wm;
    }
    AB[i * 128 + j] = make_float2(aa, ba);
    MB[i * 128 + j] = make_float2(am, bm);
}

// ---------------------------------------------------------------------------
// node_gemm: qa/ka/va = h @ {Wqa,Wka,Wva} + bias. Transposed LDS tile
// hsT[k][r] (pad 36 -> 16B-aligned rows) so per-k reads are 4x ds_read_b128.
// ---------------------------------------------------------------------------
__global__ __launch_bounds__(256) void node_gemm(
    const float* __restrict__ h, int N,
    const float* __restrict__ Wqa, const float* __restrict__ Wka, const float* __restrict__ Wva,
    const float* __restrict__ bqa, const float* __restrict__ bka, const float* __restrict__ bva,
    float* __restrict__ qa, float* __restrict__ ka, float* __restrict__ va)
{
    __shared__ float hsT[D][36];
    int r0 = blockIdx.x * RPB;
    int t = threadIdx.x;
    for (int x = t; x < RPB * D; x += 256) {
        int r = x >> 7, cc = x & 127;
        hsT[cc][r] = (r0 + r < N) ? h[(size_t)(r0 + r) * D + cc] : 0.f;
    }
    __syncthreads();
    int c = t & 127;
    int half = t >> 7;
    float acc0[16], acc1[16], acc2[16];
#pragma unroll
    for (int r = 0; r < 16; r++) { acc0[r] = 0.f; acc1[r] = 0.f; acc2[r] = 0.f; }
    for (int k = 0; k < D; k++) {
        float w0 = Wqa[k * D + c], w1 = Wka[k * D + c], w2 = Wva[k * D + c];
        const float4* hp = (const float4*)&hsT[k][half * 16];
#pragma unroll
        for (int p = 0; p < 4; p++) {
            float4 hv = hp[p];
            acc0[p * 4 + 0] += hv.x * w0; acc1[p * 4 + 0] += hv.x * w1; acc2[p * 4 + 0] += hv.x * w2;
            acc0[p * 4 + 1] += hv.y * w0; acc1[p * 4 + 1] += hv.y * w1; acc2[p * 4 + 1] += hv.y * w2;
            acc0[p * 4 + 2] += hv.z * w0; acc1[p * 4 + 2] += hv.z * w1; acc2[p * 4 + 2] += hv.z * w2;
            acc0[p * 4 + 3] += hv.w * w0; acc1[p * 4 + 3] += hv.w * w1; acc2[p * 4 + 3] += hv.w * w2;
        }
    }
    float b0 = bqa[c], b1 = bka[c], b2 = bva[c];
#pragma unroll
    for (int r = 0; r < 16; r++) {
        int row = r0 + half * 16 + r;
        if (row < N) {
            qa[(size_t)row * D + c] = acc0[r] + b0;
            ka[(size_t)row * D + c] = acc1[r] + b1;
            va[(size_t)row * D + c] = acc2[r] + b2;
        }
    }
}

// ---------------------------------------------------------------------------
// CSR build: histogram -> 3-phase multi-block scan -> scatter packed records
// ---------------------------------------------------------------------------
__global__ __launch_bounds__(256) void k_hist(const int* __restrict__ ei, int E,
                                              int* __restrict__ deg)
{
    int e = blockIdx.x * 256 + threadIdx.x;
    if (e < E) atomicAdd(deg + ei[E + e], 1);
}

__global__ __launch_bounds__(SB) void k_scan1(const int* __restrict__ deg, int N,
                                              int* __restrict__ partial)
{
    __shared__ int ls[SB];
    int t = threadIdx.x;
    int i = blockIdx.x * SB + t;
    ls[t] = (i < N) ? deg[i] : 0;
    __syncthreads();
    for (int s = SB / 2; s > 0; s >>= 1) {
        if (t < s) ls[t] += ls[t + s];
        __syncthreads();
    }
    if (t == 0) partial[blockIdx.x] = ls[0];
}

__global__ __launch_bounds__(256) void k_scan2(const int* __restrict__ partial, int NB,
                                               int* __restrict__ base, int* __restrict__ off, int N)
{
    __shared__ int ls[256];
    int t = threadIdx.x;
    int v = (t < NB) ? partial[t] : 0;
    ls[t] = v;
    __syncthreads();
    int val = v;
    for (int s = 1; s < 256; s <<= 1) {
        int add = (t >= s) ? ls[t - s] : 0;
        __syncthreads();
        val += add;
        ls[t] = val;
        __syncthreads();
    }
    base[t] = val - v;
    if (t == NB - 1) off[N] = val;
}

__global__ __launch_bounds__(SB) void k_scan3(const int* __restrict__ deg, int N,
                                              const int* __restrict__ base,
                                              int* __restrict__ off, int* __restrict__ cur)
{
    __shared__ int ls[SB];
    int t = threadIdx.x;
    int i = blockIdx.x * SB + t;
    int v = (i < N) ? deg[i] : 0;
    ls[t] = v;
    __syncthreads();
    int val = v;
    for (int s = 1; s < SB; s <<= 1) {
        int add = (t >= s) ? ls[t - s] : 0;
        __syncthreads();
        val += add;
        ls[t] = val;
        __syncthreads();
    }
    int ex = base[blockIdx.x] + val - v;
    if (i < N) { off[i] = ex; cur[i] = ex; }
}

// scatter packed records {row_byte_off, bits(a), table_byte_off} into CSR slots
__global__ __launch_bounds__(256) void k_scatter(const int* __restrict__ ei,
                                                 const float* __restrict__ eattr, int E,
                                                 const float* __restrict__ bounds,
                                                 int* __restrict__ cur, int4* __restrict__ recs)
{
    __shared__ float b[130];
    int t = threadIdx.x;
    if (t < 130) b[t] = bounds[t];
    __syncthreads();
    int e = blockIdx.x * 256 + t;
    if (e >= E) return;
    int row = ei[e], col = ei[E + e];
    float a = eattr[e];
    int lo = 0, hi = 128;
    while (lo < hi) { int mid = (lo + hi + 1) >> 1; if (b[mid] <= a) lo = mid; else hi = mid - 1; }
    int p = atomicAdd(cur + col, 1);
    recs[p] = make_int4(row * (D * 4), __float_as_int(a), lo << 10, 0);
}

// ---------------------------------------------------------------------------
// node_all: 32 lanes per destination node (2 nodes per wave), float4 per lane.
// Single-pass flash-style online softmax + silu message aggregation.
// Per edge: rec + k4 + v4 + 2xAB4 + 2xMB4 wide loads; 5-round shfl reduce.
// No LDS, no atomics, no second pass.
// ---------------------------------------------------------------------------
__global__ __launch_bounds__(256) void node_all(
    const int4* __restrict__ recs, int N,
    const int* __restrict__ off,
    const float* __restrict__ qa, const float* __restrict__ ka, const float* __restrict__ va,
    const float2* __restrict__ AB, const float2* __restrict__ MB,
    const float* __restrict__ Wa2, const float* __restrict__ ba2,
    float* __restrict__ S, float* __restrict__ segsum)
{
    int t = threadIdx.x;
    int lane = t & 63, wv = t >> 6;
    int l = lane & 31;                       // lane within half-wave
    int n = blockIdx.x * 8 + wv * 2 + (lane >> 5);
    bool valid = (n < N);
    int start = valid ? off[n] : 0;
    int end   = valid ? off[n + 1] : 0;

    const char* kac = (const char*)ka;
    const char* vac = (const char*)va;
    const char* ABc = (const char*)AB;
    const char* MBc = (const char*)MB;

    float4 q4 = valid ? *(const float4*)(qa + (size_t)n * D + 4 * l)
                      : make_float4(0.f, 0.f, 0.f, 0.f);
    float4 w4 = *(const float4*)(Wa2 + 4 * l);
    float ba2v = ba2[0];

    float m_run = -INFINITY;
    float a0 = 0.f, a1 = 0.f, a2 = 0.f, a3 = 0.f, ssum = 0.f;

    for (int idx = start; idx < end; idx++) {
        int4 rec = recs[idx];
        float a = __int_as_float(rec.y);
        float4 k4 = *(const float4*)(kac + rec.x + (l << 4));
        float4 ab0 = *(const float4*)(ABc + rec.z + (l << 5));
        float4 ab1 = *(const float4*)(ABc + rec.z + (l << 5) + 16);
        float4 v4 = *(const float4*)(vac + rec.x + (l << 4));
        float4 mb0 = *(const float4*)(MBc + rec.z + (l << 5));
        float4 mb1 = *(const float4*)(MBc + rec.z + (l << 5) + 16);

        // logit partial: relu(q + k + a*A + B) . w   (elements 4l..4l+3)
        float part = fmaxf(q4.x + k4.x + a * ab0.x + ab0.y, 0.f) * w4.x
                   + fmaxf(q4.y + k4.y + a * ab0.z + ab0.w, 0.f) * w4.y
                   + fmaxf(q4.z + k4.z + a * ab1.x + ab1.y, 0.f) * w4.z
                   + fmaxf(q4.w + k4.w + a * ab1.z + ab1.w, 0.f) * w4.w;
#pragma unroll
        for (int s = 1; s < 32; s <<= 1) part += __shfl_xor(part, s, 64);
        float lg = part + ba2v;

        // online softmax update
        float mN = fmaxf(m_run, lg);
        float sc = __expf(m_run - mN);
        float ex = __expf(lg - mN);
        m_run = mN;

        // silu message
        float x0 = v4.x + a * mb0.x + mb0.y;
        float x1 = v4.y + a * mb0.z + mb0.w;
        float x2 = v4.z + a * mb1.x + mb1.y;
        float x3 = v4.w + a * mb1.z + mb1.w;
        float s0 = x0 * __builtin_amdgcn_rcpf(1.f + __expf(-x0));
        float s1 = x1 * __builtin_amdgcn_rcpf(1.f + __expf(-x1));
        float s2 = x2 * __builtin_amdgcn_rcpf(1.f + __expf(-x2));
        float s3 = x3 * __builtin_amdgcn_rcpf(1.f + __expf(-x3));

        a0 = a0 * sc + ex * s0;
        a1 = a1 * sc + ex * s1;
        a2 = a2 * sc + ex * s2;
        a3 = a3 * sc + ex * s3;
        ssum = ssum * sc + ex;
    }

    if (valid) {
        float inv = __builtin_amdgcn_rcpf(ssum + 1e-16f);
        *(float4*)(S + (size_t)n * D + 4 * l) =
            make_float4(a0 * inv, a1 * inv, a2 * inv, a3 * inv);
        if (l == 0) segsum[n] = ssum;
    }
}

// ---------------------------------------------------------------------------
// node_out: out = h + S@Wm2 + bm2 * (segsum/(segsum+1e-16)); blocks >= G1
// copy pos into the tail of d_out.
// ---------------------------------------------------------------------------
__global__ __launch_bounds__(256) void node_out(
    const float* __restrict__ h, int N,
    const float* __restrict__ S, const float* __restrict__ Wm2, const float* __restrict__ bm2,
    const float* __restrict__ segsum, float* __restrict__ out,
    const float* __restrict__ pos, int npos, int G1)
{
    int b = blockIdx.x;
    if (b >= G1) {
        int i = ((b - G1) * 256 + threadIdx.x) * 4;
        float* outp = out + (size_t)N * D;
        if (i + 3 < npos) {
            *(float4*)(outp + i) = *(const float4*)(pos + i);
        } else {
            for (int j = i; j < npos; j++) outp[j] = pos[j];
        }
        return;
    }
    __shared__ float hsT[D][36];
    int r0 = b * RPB;
    int t = threadIdx.x;
    for (int x = t; x < RPB * D; x += 256) {
        int r = x >> 7, cc = x & 127;
        hsT[cc][r] = (r0 + r < N) ? S[(size_t)(r0 + r) * D + cc] : 0.f;
    }
    __syncthreads();
    int c = t & 127, half = t >> 7;
    float acc[16];
#pragma unroll
    for (int r = 0; r < 16; r++) acc[r] = 0.f;
    for (int k = 0; k < D; k++) {
        float w = Wm2[k * D + c];
        const float4* hp = (const float4*)&hsT[k][half * 16];
#pragma unroll
        for (int p = 0; p < 4; p++) {
            float4 hv = hp[p];
            acc[p * 4 + 0] += hv.x * w;
            acc[p * 4 + 1] += hv.y * w;
            acc[p * 4 + 2] += hv.z * w;
            acc[p * 4 + 3] += hv.w * w;
        }
    }
    float bb = bm2[c];
#pragma unroll
    for (int r = 0; r < 16; r++) {
        int row = r0 + half * 16 + r;
        if (row < N) {
            float ws = segsum[row];
            ws = ws / (ws + 1e-16f);
            out[(size_t)row * D + c] = h[(size_t)row * D + c] + acc[r] + bb * ws;
        }
    }
}

extern "C" void kernel_launch(void* const* d_in, const int* in_sizes, int n_in,
                              void* d_out, int out_size, void* d_ws, size_t ws_size,
                              hipStream_t stream)
{
    const float* h     = (const float*)d_in[0];
    const float* pos   = (const float*)d_in[1];
    const int*   ei    = (const int*)d_in[2];
    const float* eattr = (const float*)d_in[3];
    const float* Wq  = (const float*)d_in[4];  const float* bq  = (const float*)d_in[5];
    const float* Wk  = (const float*)d_in[6];  const float* bk  = (const float*)d_in[7];
    const float* Wv  = (const float*)d_in[8];  const float* bv  = (const float*)d_in[9];
    const float* We1 = (const float*)d_in[10]; const float* be1 = (const float*)d_in[11];
    const float* We2 = (const float*)d_in[12]; const float* be2 = (const float*)d_in[13];
    const float* Wa1 = (const float*)d_in[14]; const float* ba1 = (const float*)d_in[15];
    const float* Wa2 = (const float*)d_in[16]; const float* ba2 = (const float*)d_in[17];
    const float* Wm1 = (const float*)d_in[18]; const float* bm1 = (const float*)d_in[19];
    const float* Wm2 = (const float*)d_in[20]; const float* bm2 = (const float*)d_in[21];

    int N = in_sizes[0] / D;
    int E = in_sizes[3];
    int NB = (N + SB - 1) / SB;

    float* ws = (float*)d_ws;
    size_t off_f = 0;
    auto alloc = [&](size_t n) { float* p = ws + off_f; off_f += (n + 63) & ~(size_t)63; return p; };

    float* Wqa = alloc(D * D); float* Wka = alloc(D * D); float* Wva = alloc(D * D);
    float* bqa = alloc(D);     float* bka = alloc(D);     float* bva = alloc(D);
    float* bounds = alloc(130);
    float2* AB = (float2*)alloc((size_t)129 * 128 * 2);
    float2* MB = (float2*)alloc((size_t)129 * 128 * 2);
    float* qa = alloc((size_t)N * D);
    float* ka = alloc((size_t)N * D);
    float* va = alloc((size_t)N * D);
    float* S  = qa;  // alias: wave reads qa row n before writing S row n; no cross-row use
    float* segsum = alloc(N);
    int* deg  = (int*)alloc(N);
    int* offs = (int*)alloc(N + 1);
    int* cur  = (int*)alloc(N);
    int* partial = (int*)alloc(256);
    int* base    = (int*)alloc(256);
    int4* recs = (int4*)alloc((size_t)E * 4);

    hipMemsetAsync(deg, 0, (size_t)N * 4, stream);

    prep_weights<<<387, 128, 0, stream>>>(Wq, bq, Wk, bk, Wv, bv, Wa1, ba1, Wm1, bm1,
                                          Wqa, Wka, Wva, bqa, bka, bva);
    prep_bounds<<<1, 128, 0, stream>>>(We1, be1, bounds);
    prep_tables<<<129, 128, 0, stream>>>(We1, be1, We2, be2, Wa1, Wm1, bounds, AB, MB);

    // CSR build
    k_hist<<<(E + 255) / 256, 256, 0, stream>>>(ei, E, deg);
    k_scan1<<<NB, SB, 0, stream>>>(deg, N, partial);
    k_scan2<<<1, 256, 0, stream>>>(partial, NB, base, offs, N);
    k_scan3<<<NB, SB, 0, stream>>>(deg, N, base, offs, cur);
    k_scatter<<<(E + 255) / 256, 256, 0, stream>>>(ei, eattr, E, bounds, cur, recs);

    node_gemm<<<(N + RPB - 1) / RPB, 256, 0, stream>>>(h, N, Wqa, Wka, Wva, bqa, bka, bva,
                                                       qa, ka, va);

    node_all<<<(N + 7) / 8, 256, 0, stream>>>(recs, N, offs, qa, ka, va, AB, MB,
                                              Wa2, ba2, S, segsum);

    int G1 = (N + RPB - 1) / RPB;
    int G2 = (2 * N + 1023) / 1024;
    node_out<<<G1 + G2, 256, 0, stream>>>(h, N, S, Wm2, bm2, segsum, (float*)d_out,
                                          pos, 2 * N, G1);
}

// Round 5
// 332.451 us; speedup vs baseline: 7.2854x; 1.0519x over previous
//
#include <hip/hip_runtime.h>
#include <math.h>

#define D 128
#define RPB 32
#define SB 256

// round-to-nearest-even f32 -> bf16 bits
__device__ inline unsigned f2bf(float f) {
    unsigned u = __float_as_uint(f);
    return (u + 0x7FFFu + ((u >> 16) & 1u)) >> 16;
}

// ---------------------------------------------------------------------------
// prep0: fused {weight folding, bounds sort, deg zeroing}.
//   blocks 0..383   : Wqa/Wka/Wva rows
//   blocks 384..386 : bqa/bka/bva
//   block  387      : bounds (bitonic sort of ReLU breakpoints)
//   blocks 388+     : deg[i] = 0
// ---------------------------------------------------------------------------
__global__ __launch_bounds__(128) void prep0(
    const float* __restrict__ Wq, const float* __restrict__ bq,
    const float* __restrict__ Wk, const float* __restrict__ bk,
    const float* __restrict__ Wv, const float* __restrict__ bv,
    const float* __restrict__ Wa1, const float* __restrict__ ba1,
    const float* __restrict__ Wm1, const float* __restrict__ bm1,
    const float* __restrict__ We1, const float* __restrict__ be1,
    float* __restrict__ Wqa, float* __restrict__ Wka, float* __restrict__ Wva,
    float* __restrict__ bqa, float* __restrict__ bka, float* __restrict__ bva,
    float* __restrict__ bounds, int* __restrict__ deg, int N)
{
    int b = blockIdx.x;
    int j = threadIdx.x;
    if (b < 384) {
        int which = b >> 7, i = b & 127;
        const float *A, *B; float *C;
        if (which == 0)      { A = Wq; B = Wa1;           C = Wqa; }
        else if (which == 1) { A = Wk; B = Wa1 + 128 * D; C = Wka; }
        else                 { A = Wv; B = Wm1;           C = Wva; }
        float acc = 0.f;
        for (int k = 0; k < D; k++) acc += A[i * D + k] * B[k * D + j];
        C[i * D + j] = acc;
    } else if (b < 387) {
        int which = b - 384;
        const float *bias, *B, *extra; float *out;
        if (which == 0)      { bias = bq; B = Wa1;           out = bqa; extra = ba1; }
        else if (which == 1) { bias = bk; B = Wa1 + 128 * D; out = bka; extra = nullptr; }
        else                 { bias = bv; B = Wm1;           out = bva; extra = bm1; }
        float acc = extra ? extra[j] : 0.f;
        for (int k = 0; k < D; k++) acc += bias[k] * B[k * D + j];
        out[j] = acc;
    } else if (b == 387) {
        __shared__ float sb[128];
        float w = We1[j], bb = be1[j];
        float t = (w != 0.f) ? (-bb / w) : 2.f;
        t = fminf(fmaxf(t, 0.f), 1.f);
        sb[j] = t;
        __syncthreads();
        for (int k = 2; k <= 128; k <<= 1)
            for (int jj = k >> 1; jj > 0; jj >>= 1) {
                int ixj = j ^ jj;
                if (ixj > j) {
                    float a = sb[j], c = sb[ixj];
                    bool up = ((j & k) == 0);
                    if (up ? (a > c) : (a < c)) { sb[j] = c; sb[ixj] = a; }
                }
                __syncthreads();
            }
        if (j == 0) { bounds[0] = 0.f; bounds[129] = 1.f; }
        bounds[1 + j] = sb[j];
    } else {
        int i = (b - 388) * 128 + j;
        if (i < N) deg[i] = 0;
    }
}

// ---------------------------------------------------------------------------
// prep_tables: per interval, e(a)=a*Ae+Be projected through Wa1_e / Wm1_e.
// Interleaved: AB[i*128+j] = {Aa,Ba}, MB[i*128+j] = {Am,Bm}.
// ---------------------------------------------------------------------------
__global__ void prep_tables(const float* __restrict__ We1, const float* __restrict__ be1,
                            const float* __restrict__ We2, const float* __restrict__ be2,
                            const float* __restrict__ Wa1, const float* __restrict__ Wm1,
                            const float* __restrict__ bounds,
                            float2* __restrict__ AB, float2* __restrict__ MB)
{
    int i = blockIdx.x;
    int j = threadIdx.x;
    __shared__ float Ae[128], Be[128];
    float m = 0.5f * (bounds[i] + bounds[i + 1]);
    float ae = 0.f, be = 0.f;
    for (int k = 0; k < 128; k++) {
        float w = We1[k], b = be1[k];
        if (m * w + b > 0.f) { ae += w * We2[k * D + j]; be += b * We2[k * D + j]; }
    }
    be += be2[j];
    Ae[j] = ae; Be[j] = be;
    __syncthreads();
    float aa = 0.f, ba = 0.f, am = 0.f, bm = 0.f;
    for (int l = 0; l < 128; l++) {
        float ael = Ae[l], bel = Be[l];
        float wa = Wa1[(256 + l) * D + j];
        float wm = Wm1[(128 + l) * D + j];
        aa += ael * wa; ba += bel * wa;
        am += ael * wm; bm += bel * wm;
    }
    AB[i * 128 + j] = make_float2(aa, ba);
    MB[i * 128 + j] = make_float2(am, bm);
}

// ---------------------------------------------------------------------------
// node_gemm: qa = h@Wqa + bqa (f32); kv[row] = interleaved bf16 pairs
// {ka_c, va_c} (4B per c) so node_all gets both operands in ONE 16B load.
// ---------------------------------------------------------------------------
__global__ __launch_bounds__(256) void node_gemm(
    const float* __restrict__ h, int N,
    const float* __restrict__ Wqa, const float* __restrict__ Wka, const float* __restrict__ Wva,
    const float* __restrict__ bqa, const float* __restrict__ bka, const float* __restrict__ bva,
    float* __restrict__ qa, unsigned* __restrict__ kv)
{
    __shared__ float hsT[D][36];
    int r0 = blockIdx.x * RPB;
    int t = threadIdx.x;
    for (int x = t; x < RPB * D; x += 256) {
        int r = x >> 7, cc = x & 127;
        hsT[cc][r] = (r0 + r < N) ? h[(size_t)(r0 + r) * D + cc] : 0.f;
    }
    __syncthreads();
    int c = t & 127;
    int half = t >> 7;
    float acc0[16], acc1[16], acc2[16];
#pragma unroll
    for (int r = 0; r < 16; r++) { acc0[r] = 0.f; acc1[r] = 0.f; acc2[r] = 0.f; }
    for (int k = 0; k < D; k++) {
        float w0 = Wqa[k * D + c], w1 = Wka[k * D + c], w2 = Wva[k * D + c];
        const float4* hp = (const float4*)&hsT[k][half * 16];
#pragma unroll
        for (int p = 0; p < 4; p++) {
            float4 hv = hp[p];
            acc0[p * 4 + 0] += hv.x * w0; acc1[p * 4 + 0] += hv.x * w1; acc2[p * 4 + 0] += hv.x * w2;
            acc0[p * 4 + 1] += hv.y * w0; acc1[p * 4 + 1] += hv.y * w1; acc2[p * 4 + 1] += hv.y * w2;
            acc0[p * 4 + 2] += hv.z * w0; acc1[p * 4 + 2] += hv.z * w1; acc2[p * 4 + 2] += hv.z * w2;
            acc0[p * 4 + 3] += hv.w * w0; acc1[p * 4 + 3] += hv.w * w1; acc2[p * 4 + 3] += hv.w * w2;
        }
    }
    float b0 = bqa[c], b1 = bka[c], b2 = bva[c];
#pragma unroll
    for (int r = 0; r < 16; r++) {
        int row = r0 + half * 16 + r;
        if (row < N) {
            qa[(size_t)row * D + c] = acc0[r] + b0;
            unsigned pk = (f2bf(acc2[r] + b2) << 16) | f2bf(acc1[r] + b1);
            kv[(size_t)row * D + c] = pk;
        }
    }
}

// ---------------------------------------------------------------------------
// CSR build: histogram -> 3-phase scan -> scatter packed 8B records
// ---------------------------------------------------------------------------
__global__ __launch_bounds__(256) void k_hist(const int* __restrict__ ei, int E,
                                              int* __restrict__ deg)
{
    int e = blockIdx.x * 256 + threadIdx.x;
    if (e < E) atomicAdd(deg + ei[E + e], 1);
}

__global__ __launch_bounds__(SB) void k_scan1(const int* __restrict__ deg, int N,
                                              int* __restrict__ partial)
{
    __shared__ int ls[SB];
    int t = threadIdx.x;
    int i = blockIdx.x * SB + t;
    ls[t] = (i < N) ? deg[i] : 0;
    __syncthreads();
    for (int s = SB / 2; s > 0; s >>= 1) {
        if (t < s) ls[t] += ls[t + s];
        __syncthreads();
    }
    if (t == 0) partial[blockIdx.x] = ls[0];
}

__global__ __launch_bounds__(256) void k_scan2(const int* __restrict__ partial, int NB,
                                               int* __restrict__ base, int* __restrict__ off, int N)
{
    __shared__ int ls[256];
    int t = threadIdx.x;
    int v = (t < NB) ? partial[t] : 0;
    ls[t] = v;
    __syncthreads();
    int val = v;
    for (int s = 1; s < 256; s <<= 1) {
        int add = (t >= s) ? ls[t - s] : 0;
        __syncthreads();
        val += add;
        ls[t] = val;
        __syncthreads();
    }
    base[t] = val - v;
    if (t == NB - 1) off[N] = val;
}

__global__ __launch_bounds__(SB) void k_scan3(const int* __restrict__ deg, int N,
                                              const int* __restrict__ base,
                                              int* __restrict__ off, int* __restrict__ cur)
{
    __shared__ int ls[SB];
    int t = threadIdx.x;
    int i = blockIdx.x * SB + t;
    int v = (i < N) ? deg[i] : 0;
    ls[t] = v;
    __syncthreads();
    int val = v;
    for (int s = 1; s < SB; s <<= 1) {
        int add = (t >= s) ? ls[t - s] : 0;
        __syncthreads();
        val += add;
        ls[t] = val;
        __syncthreads();
    }
    int ex = base[blockIdx.x] + val - v;
    if (i < N) { off[i] = ex; cur[i] = ex; }
}

// scatter packed records {row | interval<<17, bits(a)} into CSR slots
__global__ __launch_bounds__(256) void k_scatter(const int* __restrict__ ei,
                                                 const float* __restrict__ eattr, int E,
                                                 const float* __restrict__ bounds,
                                                 int* __restrict__ cur, int2* __restrict__ recs)
{
    __shared__ float b[130];
    int t = threadIdx.x;
    if (t < 130) b[t] = bounds[t];
    __syncthreads();
    int e = blockIdx.x * 256 + t;
    if (e >= E) return;
    int row = ei[e], col = ei[E + e];
    float a = eattr[e];
    int lo = 0, hi = 128;
    while (lo < hi) { int mid = (lo + hi + 1) >> 1; if (b[mid] <= a) lo = mid; else hi = mid - 1; }
    int p = atomicAdd(cur + col, 1);
    recs[p] = make_int2(row | (lo << 17), __float_as_int(a));
}

// ---------------------------------------------------------------------------
// node_all: 32 lanes per destination node (2 nodes/wave). Single-pass online
// softmax + silu message aggregation. Per edge per lane: one 8B rec
// (half-wave broadcast), ONE 16B kv load (bf16 ka|va interleaved), 4x16B
// L2-resident table loads. No LDS, no atomics.
// ---------------------------------------------------------------------------
__global__ __launch_bounds__(256) void node_all(
    const int2* __restrict__ recs, int N,
    const int* __restrict__ off,
    const float* __restrict__ qa, const unsigned* __restrict__ kv,
    const float2* __restrict__ AB, const float2* __restrict__ MB,
    const float* __restrict__ Wa2, const float* __restrict__ ba2,
    float* __restrict__ S, float* __restrict__ segsum)
{
    int t = threadIdx.x;
    int lane = t & 63, wv = t >> 6;
    int l = lane & 31;
    int n = blockIdx.x * 8 + wv * 2 + (lane >> 5);
    bool valid = (n < N);
    int start = valid ? off[n] : 0;
    int end   = valid ? off[n + 1] : 0;

    const char* kvc = (const char*)kv;
    const char* ABc = (const char*)AB;
    const char* MBc = (const char*)MB;

    float4 q4 = valid ? *(const float4*)(qa + (size_t)n * D + 4 * l)
                      : make_float4(0.f, 0.f, 0.f, 0.f);
    float4 w4 = *(const float4*)(Wa2 + 4 * l);
    float ba2v = ba2[0];

    float m_run = -INFINITY;
    float a0 = 0.f, a1 = 0.f, a2 = 0.f, a3 = 0.f, ssum = 0.f;

    for (int idx = start; idx < end; idx++) {
        int2 rec = recs[idx];
        unsigned w0 = (unsigned)rec.x;
        float a = __int_as_float(rec.y);
        int rowb = (int)(w0 & 0x1FFFFu) << 9;   // row * 512
        int tabb = (int)(w0 >> 17) << 10;       // interval * 1024

        uint4 kvp = *(const uint4*)(kvc + rowb + (l << 4));
        float4 ab0 = *(const float4*)(ABc + tabb + (l << 5));
        float4 ab1 = *(const float4*)(ABc + tabb + (l << 5) + 16);
        float4 mb0 = *(const float4*)(MBc + tabb + (l << 5));
        float4 mb1 = *(const float4*)(MBc + tabb + (l << 5) + 16);

        float k0 = __uint_as_float(kvp.x << 16);
        float v0 = __uint_as_float(kvp.x & 0xFFFF0000u);
        float k1 = __uint_as_float(kvp.y << 16);
        float v1 = __uint_as_float(kvp.y & 0xFFFF0000u);
        float k2 = __uint_as_float(kvp.z << 16);
        float v2 = __uint_as_float(kvp.z & 0xFFFF0000u);
        float k3 = __uint_as_float(kvp.w << 16);
        float v3 = __uint_as_float(kvp.w & 0xFFFF0000u);

        // logit partial: relu(q + k + a*A + B) . w
        float part = fmaxf(q4.x + k0 + a * ab0.x + ab0.y, 0.f) * w4.x
                   + fmaxf(q4.y + k1 + a * ab0.z + ab0.w, 0.f) * w4.y
                   + fmaxf(q4.z + k2 + a * ab1.x + ab1.y, 0.f) * w4.z
                   + fmaxf(q4.w + k3 + a * ab1.z + ab1.w, 0.f) * w4.w;
#pragma unroll
        for (int s = 1; s < 32; s <<= 1) part += __shfl_xor(part, s, 64);
        float lg = part + ba2v;

        // online softmax update
        float mN = fmaxf(m_run, lg);
        float sc = __expf(m_run - mN);
        float ex = __expf(lg - mN);
        m_run = mN;

        // silu message
        float x0 = v0 + a * mb0.x + mb0.y;
        float x1 = v1 + a * mb0.z + mb0.w;
        float x2 = v2 + a * mb1.x + mb1.y;
        float x3 = v3 + a * mb1.z + mb1.w;
        float s0 = x0 * __builtin_amdgcn_rcpf(1.f + __expf(-x0));
        float s1 = x1 * __builtin_amdgcn_rcpf(1.f + __expf(-x1));
        float s2 = x2 * __builtin_amdgcn_rcpf(1.f + __expf(-x2));
        float s3 = x3 * __builtin_amdgcn_rcpf(1.f + __expf(-x3));

        a0 = a0 * sc + ex * s0;
        a1 = a1 * sc + ex * s1;
        a2 = a2 * sc + ex * s2;
        a3 = a3 * sc + ex * s3;
        ssum = ssum * sc + ex;
    }

    if (valid) {
        float inv = __builtin_amdgcn_rcpf(ssum + 1e-16f);
        *(float4*)(S + (size_t)n * D + 4 * l) =
            make_float4(a0 * inv, a1 * inv, a2 * inv, a3 * inv);
        if (l == 0) segsum[n] = ssum;
    }
}

// ---------------------------------------------------------------------------
// node_out: out = h + S@Wm2 + bm2 * (segsum/(segsum+1e-16)); tail blocks
// copy pos into d_out.
// ---------------------------------------------------------------------------
__global__ __launch_bounds__(256) void node_out(
    const float* __restrict__ h, int N,
    const float* __restrict__ S, const float* __restrict__ Wm2, const float* __restrict__ bm2,
    const float* __restrict__ segsum, float* __restrict__ out,
    const float* __restrict__ pos, int npos, int G1)
{
    int b = blockIdx.x;
    if (b >= G1) {
        int i = ((b - G1) * 256 + threadIdx.x) * 4;
        float* outp = out + (size_t)N * D;
        if (i + 3 < npos) {
            *(float4*)(outp + i) = *(const float4*)(pos + i);
        } else {
            for (int j = i; j < npos; j++) outp[j] = pos[j];
        }
        return;
    }
    __shared__ float hsT[D][36];
    int r0 = b * RPB;
    int t = threadIdx.x;
    for (int x = t; x < RPB * D; x += 256) {
        int r = x >> 7, cc = x & 127;
        hsT[cc][r] = (r0 + r < N) ? S[(size_t)(r0 + r) * D + cc] : 0.f;
    }
    __syncthreads();
    int c = t & 127, half = t >> 7;
    float acc[16];
#pragma unroll
    for (int r = 0; r < 16; r++) acc[r] = 0.f;
    for (int k = 0; k < D; k++) {
        float w = Wm2[k * D + c];
        const float4* hp = (const float4*)&hsT[k][half * 16];
#pragma unroll
        for (int p = 0; p < 4; p++) {
            float4 hv = hp[p];
            acc[p * 4 + 0] += hv.x * w;
            acc[p * 4 + 1] += hv.y * w;
            acc[p * 4 + 2] += hv.z * w;
            acc[p * 4 + 3] += hv.w * w;
        }
    }
    float bb = bm2[c];
#pragma unroll
    for (int r = 0; r < 16; r++) {
        int row = r0 + half * 16 + r;
        if (row < N) {
            float ws = segsum[row];
            ws = ws / (ws + 1e-16f);
            out[(size_t)row * D + c] = h[(size_t)row * D + c] + acc[r] + bb * ws;
        }
    }
}

extern "C" void kernel_launch(void* const* d_in, const int* in_sizes, int n_in,
                              void* d_out, int out_size, void* d_ws, size_t ws_size,
                              hipStream_t stream)
{
    const float* h     = (const float*)d_in[0];
    const float* pos   = (const float*)d_in[1];
    const int*   ei    = (const int*)d_in[2];
    const float* eattr = (const float*)d_in[3];
    const float* Wq  = (const float*)d_in[4];  const float* bq  = (const float*)d_in[5];
    const float* Wk  = (const float*)d_in[6];  const float* bk  = (const float*)d_in[7];
    const float* Wv  = (const float*)d_in[8];  const float* bv  = (const float*)d_in[9];
    const float* We1 = (const float*)d_in[10]; const float* be1 = (const float*)d_in[11];
    const float* We2 = (const float*)d_in[12]; const float* be2 = (const float*)d_in[13];
    const float* Wa1 = (const float*)d_in[14]; const float* ba1 = (const float*)d_in[15];
    const float* Wa2 = (const float*)d_in[16]; const float* ba2 = (const float*)d_in[17];
    const float* Wm1 = (const float*)d_in[18]; const float* bm1 = (const float*)d_in[19];
    const float* Wm2 = (const float*)d_in[20]; const float* bm2 = (const float*)d_in[21];

    int N = in_sizes[0] / D;
    int E = in_sizes[3];
    int NB = (N + SB - 1) / SB;

    float* ws = (float*)d_ws;
    size_t off_f = 0;
    auto alloc = [&](size_t n) { float* p = ws + off_f; off_f += (n + 63) & ~(size_t)63; return p; };

    float* Wqa = alloc(D * D); float* Wka = alloc(D * D); float* Wva = alloc(D * D);
    float* bqa = alloc(D);     float* bka = alloc(D);     float* bva = alloc(D);
    float* bounds = alloc(130);
    float2* AB = (float2*)alloc((size_t)129 * 128 * 2);
    float2* MB = (float2*)alloc((size_t)129 * 128 * 2);
    float* qa = alloc((size_t)N * D);
    unsigned* kv = (unsigned*)alloc((size_t)N * D);
    float* S  = qa;  // alias: wave reads qa row n before writing S row n
    float* segsum = alloc(N);
    int* deg  = (int*)alloc(N);
    int* offs = (int*)alloc(N + 1);
    int* cur  = (int*)alloc(N);
    int* partial = (int*)alloc(256);
    int* base    = (int*)alloc(256);
    int2* recs = (int2*)alloc((size_t)E * 2);

    int G0 = 388 + (N + 127) / 128;
    prep0<<<G0, 128, 0, stream>>>(Wq, bq, Wk, bk, Wv, bv, Wa1, ba1, Wm1, bm1, We1, be1,
                                  Wqa, Wka, Wva, bqa, bka, bva, bounds, deg, N);
    prep_tables<<<129, 128, 0, stream>>>(We1, be1, We2, be2, Wa1, Wm1, bounds, AB, MB);

    // CSR build
    k_hist<<<(E + 255) / 256, 256, 0, stream>>>(ei, E, deg);
    k_scan1<<<NB, SB, 0, stream>>>(deg, N, partial);
    k_scan2<<<1, 256, 0, stream>>>(partial, NB, base, offs, N);
    k_scan3<<<NB, SB, 0, stream>>>(deg, N, base, offs, cur);
    k_scatter<<<(E + 255) / 256, 256, 0, stream>>>(ei, eattr, E, bounds, cur, recs);

    node_gemm<<<(N + RPB - 1) / RPB, 256, 0, stream>>>(h, N, Wqa, Wka, Wva, bqa, bka, bva,
                                                       qa, kv);

    node_all<<<(N + 7) / 8, 256, 0, stream>>>(recs, N, offs, qa, kv, AB, MB,
                                              Wa2, ba2, S, segsum);

    int G1 = (N + RPB - 1) / RPB;
    int G2 = (2 * N + 1023) / 1024;
    node_out<<<G1 + G2, 256, 0, stream>>>(h, N, S, Wm2, bm2, segsum, (float*)d_out,
                                          pos, 2 * N, G1);
}

// Round 6
// 299.524 us; speedup vs baseline: 8.0863x; 1.1099x over previous
//
#include <hip/hip_runtime.h>
#include <math.h>

#define D 128
#define RPB 32
#define SB 256

typedef __attribute__((ext_vector_type(8))) short bf16x8;
typedef __attribute__((ext_vector_type(4))) float f32x4;

// round-to-nearest-even f32 -> bf16 bits
__device__ inline unsigned f2bf(float f) {
    unsigned u = __float_as_uint(f);
    return (u + 0x7FFFu + ((u >> 16) & 1u)) >> 16;
}

// ---------------------------------------------------------------------------
// prep: one kernel for all precompute.
//   blocks [0,384)   : folded weights -> bf16 B-fragment-packed Wpk
//                      Wpk[((nt*4+ks)*64+lane)*8+j8] = W[k][n],
//                      k=ks*32+((lane>>4)&3)*8+j8, n=nt*16+(lane&15)
//   blocks [384,387) : biases bqa/bka/bva (f32)
//   block  387       : global bounds[] (for k_scatter)
//   blocks [388,517) : interval tables AB/MB (recompute bounds locally)
//   blocks 517+      : deg[i] = 0
// ---------------------------------------------------------------------------
__global__ __launch_bounds__(128) void prep(
    const float* __restrict__ Wq, const float* __restrict__ bq,
    const float* __restrict__ Wk, const float* __restrict__ bk,
    const float* __restrict__ Wv, const float* __restrict__ bv,
    const float* __restrict__ Wa1, const float* __restrict__ ba1,
    const float* __restrict__ Wm1, const float* __restrict__ bm1,
    const float* __restrict__ We1, const float* __restrict__ be1,
    const float* __restrict__ We2, const float* __restrict__ be2,
    ushort* __restrict__ Wpk,
    float* __restrict__ bqa, float* __restrict__ bka, float* __restrict__ bva,
    float* __restrict__ bounds,
    float2* __restrict__ AB, float2* __restrict__ MB,
    int* __restrict__ deg, int N)
{
    int b = blockIdx.x;
    int j = threadIdx.x;
    if (b < 384) {
        int which = b >> 7, i = b & 127;   // i = k index
        const float *A, *B;
        if (which == 0)      { A = Wq; B = Wa1; }
        else if (which == 1) { A = Wk; B = Wa1 + 128 * D; }
        else                 { A = Wv; B = Wm1; }
        float acc = 0.f;
        for (int k = 0; k < D; k++) acc += A[i * D + k] * B[k * D + j];
        int gc = which * 128 + j;
        int nt = gc >> 4;
        int ks = i >> 5;
        int lane = (((i >> 3) & 3) << 4) | (gc & 15);
        int j8 = i & 7;
        Wpk[((nt * 4 + ks) * 64 + lane) * 8 + j8] = (ushort)f2bf(acc);
    } else if (b < 387) {
        int which = b - 384;
        const float *bias, *B, *extra; float *out;
        if (which == 0)      { bias = bq; B = Wa1;           out = bqa; extra = ba1; }
        else if (which == 1) { bias = bk; B = Wa1 + 128 * D; out = bka; extra = nullptr; }
        else                 { bias = bv; B = Wm1;           out = bva; extra = bm1; }
        float acc = extra ? extra[j] : 0.f;
        for (int k = 0; k < D; k++) acc += bias[k] * B[k * D + j];
        out[j] = acc;
    } else if (b == 387) {
        __shared__ float sb[128];
        float w = We1[j], bb = be1[j];
        float t = (w != 0.f) ? (-bb / w) : 2.f;
        t = fminf(fmaxf(t, 0.f), 1.f);
        sb[j] = t;
        __syncthreads();
        for (int k = 2; k <= 128; k <<= 1)
            for (int jj = k >> 1; jj > 0; jj >>= 1) {
                int ixj = j ^ jj;
                if (ixj > j) {
                    float a = sb[j], c = sb[ixj];
                    bool up = ((j & k) == 0);
                    if (up ? (a > c) : (a < c)) { sb[j] = c; sb[ixj] = a; }
                }
                __syncthreads();
            }
        if (j == 0) { bounds[0] = 0.f; bounds[129] = 1.f; }
        bounds[1 + j] = sb[j];
    } else if (b < 517) {
        // interval tables; recompute bounds locally to avoid cross-block dep
        __shared__ float sb[128];
        __shared__ float Ae[128], Be[128];
        float w = We1[j], bb = be1[j];
        float t = (w != 0.f) ? (-bb / w) : 2.f;
        t = fminf(fmaxf(t, 0.f), 1.f);
        sb[j] = t;
        __syncthreads();
        for (int k = 2; k <= 128; k <<= 1)
            for (int jj = k >> 1; jj > 0; jj >>= 1) {
                int ixj = j ^ jj;
                if (ixj > j) {
                    float a = sb[j], c = sb[ixj];
                    bool up = ((j & k) == 0);
                    if (up ? (a > c) : (a < c)) { sb[j] = c; sb[ixj] = a; }
                }
                __syncthreads();
            }
        int i = b - 388;                  // interval 0..128
        float lo = (i == 0)   ? 0.f : sb[i - 1];
        float hi = (i == 128) ? 1.f : sb[i];
        float m = 0.5f * (lo + hi);
        float ae = 0.f, be = 0.f;
        for (int k = 0; k < 128; k++) {
            float ww = We1[k], bb2 = be1[k];
            if (m * ww + bb2 > 0.f) { ae += ww * We2[k * D + j]; be += bb2 * We2[k * D + j]; }
        }
        be += be2[j];
        Ae[j] = ae; Be[j] = be;
        __syncthreads();
        float aa = 0.f, ba = 0.f, am = 0.f, bm = 0.f;
        for (int l = 0; l < 128; l++) {
            float ael = Ae[l], bel = Be[l];
            float wa = Wa1[(256 + l) * D + j];
            float wm = Wm1[(128 + l) * D + j];
            aa += ael * wa; ba += bel * wa;
            am += ael * wm; bm += bel * wm;
        }
        AB[i * 128 + j] = make_float2(aa, ba);
        MB[i * 128 + j] = make_float2(am, bm);
    } else {
        int i = (b - 517) * 128 + j;
        if (i < N) deg[i] = 0;
    }
}

// ---------------------------------------------------------------------------
// node_gemm (MFMA): [N x 128] @ [128 x 384] in bf16, f32 accum.
// h staged as bf16 in LDS with XOR-swizzled 16B granules (2-way max conflict).
// B-fragments read straight from L2-resident Wpk. Epilogue writes qa (f32)
// and packed bf16 kv.
// ---------------------------------------------------------------------------
__global__ __launch_bounds__(256) void node_gemm(
    const float* __restrict__ h, int N,
    const ushort* __restrict__ Wpk,
    const float* __restrict__ bqa, const float* __restrict__ bka, const float* __restrict__ bva,
    float* __restrict__ qa, unsigned* __restrict__ kv)
{
    __shared__ __align__(16) ushort hsb[64 * 128];
    int t = threadIdx.x;
    int row0 = blockIdx.x * 64;
    // stage 64x128 f32 -> bf16, 1024 granules of 8 elems, 4 per thread
#pragma unroll
    for (int i = 0; i < 4; i++) {
        int g = t + i * 256;
        int r = g >> 4, c = g & 15;
        int grow = row0 + r;
        float4 f0, f1;
        if (grow < N) {
            const float4* hp = (const float4*)(h + (size_t)grow * D + c * 8);
            f0 = hp[0]; f1 = hp[1];
        } else {
            f0 = make_float4(0.f, 0.f, 0.f, 0.f); f1 = f0;
        }
        ushort u[8] = { (ushort)f2bf(f0.x), (ushort)f2bf(f0.y), (ushort)f2bf(f0.z), (ushort)f2bf(f0.w),
                        (ushort)f2bf(f1.x), (ushort)f2bf(f1.y), (ushort)f2bf(f1.z), (ushort)f2bf(f1.w) };
        int pc = c ^ (r & 15);
        *(uint4*)&hsb[r * 128 + pc * 8] = *(uint4*)u;
    }
    __syncthreads();

    int w = t >> 6, l = t & 63;
    int lrow = w * 16 + (l & 15);
    f32x4 acc[24];
#pragma unroll
    for (int i = 0; i < 24; i++) acc[i] = (f32x4){0.f, 0.f, 0.f, 0.f};

    const bf16x8* WB = (const bf16x8*)Wpk;
#pragma unroll
    for (int ks = 0; ks < 4; ks++) {
        int c = (ks * 4 + (l >> 4)) ^ (l & 15);
        bf16x8 afrag = *(const bf16x8*)&hsb[lrow * 128 + c * 8];
#pragma unroll
        for (int nt = 0; nt < 24; nt++) {
            bf16x8 bfrag = WB[(nt * 4 + ks) * 64 + l];
            acc[nt] = __builtin_amdgcn_mfma_f32_16x16x32_bf16(afrag, bfrag, acc[nt], 0, 0, 0);
        }
    }

    // epilogue: D layout col=lane&15, row=(lane>>4)*4+reg
    int rbase = row0 + w * 16 + ((l >> 4) << 2);
    int cl = l & 15;
#pragma unroll
    for (int cc = 0; cc < 8; cc++) {
        float bqv = bqa[cc * 16 + cl];
        float bkv = bka[cc * 16 + cl];
        float bvv = bva[cc * 16 + cl];
        f32x4 aq = acc[cc], ak = acc[8 + cc], av = acc[16 + cc];
#pragma unroll
        for (int r = 0; r < 4; r++) {
            int row = rbase + r;
            if (row < N) {
                qa[(size_t)row * D + cc * 16 + cl] = aq[r] + bqv;
                kv[(size_t)row * D + cc * 16 + cl] =
                    (f2bf(av[r] + bvv) << 16) | f2bf(ak[r] + bkv);
            }
        }
    }
}

// ---------------------------------------------------------------------------
// CSR build: histogram -> block sums -> fused scan -> scatter.
// off[] holds EXCLUSIVE starts after k_scan23; k_scatter atomically bumps
// off[col], so afterwards off[n] = inclusive end of segment n.
// ---------------------------------------------------------------------------
__global__ __launch_bounds__(256) void k_hist(const int* __restrict__ ei, int E,
                                              int* __restrict__ deg)
{
    int e = blockIdx.x * 256 + threadIdx.x;
    if (e < E) atomicAdd(deg + ei[E + e], 1);
}

__global__ __launch_bounds__(SB) void k_scan1(const int* __restrict__ deg, int N,
                                              int* __restrict__ partial)
{
    __shared__ int ls[SB];
    int t = threadIdx.x;
    int i = blockIdx.x * SB + t;
    ls[t] = (i < N) ? deg[i] : 0;
    __syncthreads();
    for (int s = SB / 2; s > 0; s >>= 1) {
        if (t < s) ls[t] += ls[t + s];
        __syncthreads();
    }
    if (t == 0) partial[blockIdx.x] = ls[0];
}

// fused: every block redundantly scans the (<=256) partials, then scans its
// own 256-node chunk and writes exclusive offsets.
__global__ __launch_bounds__(SB) void k_scan23(const int* __restrict__ deg, int N,
                                               const int* __restrict__ partial, int NB,
                                               int* __restrict__ off)
{
    __shared__ int lp[SB];
    __shared__ int ls[SB];
    int t = threadIdx.x;
    int pv = (t < NB) ? partial[t] : 0;
    lp[t] = pv;
    __syncthreads();
    int pval = pv;
    for (int s = 1; s < SB; s <<= 1) {
        int add = (t >= s) ? lp[t - s] : 0;
        __syncthreads();
        pval += add;
        lp[t] = pval;
        __syncthreads();
    }
    int base = (blockIdx.x > 0) ? lp[blockIdx.x - 1] : 0;

    int i = blockIdx.x * SB + t;
    int v = (i < N) ? deg[i] : 0;
    ls[t] = v;
    __syncthreads();
    int val = v;
    for (int s = 1; s < SB; s <<= 1) {
        int add = (t >= s) ? ls[t - s] : 0;
        __syncthreads();
        val += add;
        ls[t] = val;
        __syncthreads();
    }
    if (i < N) off[i] = base + val - v;
}

// scatter packed records {row | interval<<17, bits(a)}; bumps off[col]
__global__ __launch_bounds__(256) void k_scatter(const int* __restrict__ ei,
                                                 const float* __restrict__ eattr, int E,
                                                 const float* __restrict__ bounds,
                                                 int* __restrict__ off, int2* __restrict__ recs)
{
    __shared__ float b[130];
    int t = threadIdx.x;
    if (t < 130) b[t] = bounds[t];
    __syncthreads();
    int e = blockIdx.x * 256 + t;
    if (e >= E) return;
    int row = ei[e], col = ei[E + e];
    float a = eattr[e];
    int lo = 0, hi = 128;
    while (lo < hi) { int mid = (lo + hi + 1) >> 1; if (b[mid] <= a) lo = mid; else hi = mid - 1; }
    int p = atomicAdd(off + col, 1);
    recs[p] = make_int2(row | (lo << 17), __float_as_int(a));
}

// ---------------------------------------------------------------------------
// node_all: 32 lanes per destination node (2 nodes/wave). Single-pass online
// softmax + silu message aggregation. start/end from post-scatter off[]:
// start = off[n-1] (or 0), end = off[n].
// ---------------------------------------------------------------------------
__global__ __launch_bounds__(256) void node_all(
    const int2* __restrict__ recs, int N,
    const int* __restrict__ off,
    const float* __restrict__ qa, const unsigned* __restrict__ kv,
    const float2* __restrict__ AB, const float2* __restrict__ MB,
    const float* __restrict__ Wa2, const float* __restrict__ ba2,
    float* __restrict__ S, float* __restrict__ segsum)
{
    int t = threadIdx.x;
    int lane = t & 63, wv = t >> 6;
    int l = lane & 31;
    int n = blockIdx.x * 8 + wv * 2 + (lane >> 5);
    bool valid = (n < N);
    int start = 0, end = 0;
    if (valid) {
        end = off[n];
        start = (n > 0) ? off[n - 1] : 0;
    }

    const char* kvc = (const char*)kv;
    const char* ABc = (const char*)AB;
    const char* MBc = (const char*)MB;

    float4 q4 = valid ? *(const float4*)(qa + (size_t)n * D + 4 * l)
                      : make_float4(0.f, 0.f, 0.f, 0.f);
    float4 w4 = *(const float4*)(Wa2 + 4 * l);
    float ba2v = ba2[0];

    float m_run = -INFINITY;
    float a0 = 0.f, a1 = 0.f, a2 = 0.f, a3 = 0.f, ssum = 0.f;

    for (int idx = start; idx < end; idx++) {
        int2 rec = recs[idx];
        unsigned w0 = (unsigned)rec.x;
        float a = __int_as_float(rec.y);
        int rowb = (int)(w0 & 0x1FFFFu) << 9;   // row * 512
        int tabb = (int)(w0 >> 17) << 10;       // interval * 1024

        uint4 kvp = *(const uint4*)(kvc + rowb + (l << 4));
        float4 ab0 = *(const float4*)(ABc + tabb + (l << 5));
        float4 ab1 = *(const float4*)(ABc + tabb + (l << 5) + 16);
        float4 mb0 = *(const float4*)(MBc + tabb + (l << 5));
        float4 mb1 = *(const float4*)(MBc + tabb + (l << 5) + 16);

        float k0 = __uint_as_float(kvp.x << 16);
        float v0 = __uint_as_float(kvp.x & 0xFFFF0000u);
        float k1 = __uint_as_float(kvp.y << 16);
        float v1 = __uint_as_float(kvp.y & 0xFFFF0000u);
        float k2 = __uint_as_float(kvp.z << 16);
        float v2 = __uint_as_float(kvp.z & 0xFFFF0000u);
        float k3 = __uint_as_float(kvp.w << 16);
        float v3 = __uint_as_float(kvp.w & 0xFFFF0000u);

        float part = fmaxf(q4.x + k0 + a * ab0.x + ab0.y, 0.f) * w4.x
                   + fmaxf(q4.y + k1 + a * ab0.z + ab0.w, 0.f) * w4.y
                   + fmaxf(q4.z + k2 + a * ab1.x + ab1.y, 0.f) * w4.z
                   + fmaxf(q4.w + k3 + a * ab1.z + ab1.w, 0.f) * w4.w;
#pragma unroll
        for (int s = 1; s < 32; s <<= 1) part += __shfl_xor(part, s, 64);
        float lg = part + ba2v;

        float mN = fmaxf(m_run, lg);
        float sc = __expf(m_run - mN);
        float ex = __expf(lg - mN);
        m_run = mN;

        float x0 = v0 + a * mb0.x + mb0.y;
        float x1 = v1 + a * mb0.z + mb0.w;
        float x2 = v2 + a * mb1.x + mb1.y;
        float x3 = v3 + a * mb1.z + mb1.w;
        float s0 = x0 * __builtin_amdgcn_rcpf(1.f + __expf(-x0));
        float s1 = x1 * __builtin_amdgcn_rcpf(1.f + __expf(-x1));
        float s2 = x2 * __builtin_amdgcn_rcpf(1.f + __expf(-x2));
        float s3 = x3 * __builtin_amdgcn_rcpf(1.f + __expf(-x3));

        a0 = a0 * sc + ex * s0;
        a1 = a1 * sc + ex * s1;
        a2 = a2 * sc + ex * s2;
        a3 = a3 * sc + ex * s3;
        ssum = ssum * sc + ex;
    }

    if (valid) {
        float inv = __builtin_amdgcn_rcpf(ssum + 1e-16f);
        *(float4*)(S + (size_t)n * D + 4 * l) =
            make_float4(a0 * inv, a1 * inv, a2 * inv, a3 * inv);
        if (l == 0) segsum[n] = ssum;
    }
}

// ---------------------------------------------------------------------------
// node_out: out = h + S@Wm2 + bm2 * (segsum/(segsum+1e-16)); tail blocks
// copy pos into d_out.
// ---------------------------------------------------------------------------
__global__ __launch_bounds__(256) void node_out(
    const float* __restrict__ h, int N,
    const float* __restrict__ S, const float* __restrict__ Wm2, const float* __restrict__ bm2,
    const float* __restrict__ segsum, float* __restrict__ out,
    const float* __restrict__ pos, int npos, int G1)
{
    int b = blockIdx.x;
    if (b >= G1) {
        int i = ((b - G1) * 256 + threadIdx.x) * 4;
        float* outp = out + (size_t)N * D;
        if (i + 3 < npos) {
            *(float4*)(outp + i) = *(const float4*)(pos + i);
        } else {
            for (int j = i; j < npos; j++) outp[j] = pos[j];
        }
        return;
    }
    __shared__ float hsT[D][36];
    int r0 = b * RPB;
    int t = threadIdx.x;
    for (int x = t; x < RPB * D; x += 256) {
        int r = x >> 7, cc = x & 127;
        hsT[cc][r] = (r0 + r < N) ? S[(size_t)(r0 + r) * D + cc] : 0.f;
    }
    __syncthreads();
    int c = t & 127, half = t >> 7;
    float acc[16];
#pragma unroll
    for (int r = 0; r < 16; r++) acc[r] = 0.f;
    for (int k = 0; k < D; k++) {
        float w = Wm2[k * D + c];
        const float4* hp = (const float4*)&hsT[k][half * 16];
#pragma unroll
        for (int p = 0; p < 4; p++) {
            float4 hv = hp[p];
            acc[p * 4 + 0] += hv.x * w;
            acc[p * 4 + 1] += hv.y * w;
            acc[p * 4 + 2] += hv.z * w;
            acc[p * 4 + 3] += hv.w * w;
        }
    }
    float bb = bm2[c];
#pragma unroll
    for (int r = 0; r < 16; r++) {
        int row = r0 + half * 16 + r;
        if (row < N) {
            float ws = segsum[row];
            ws = ws / (ws + 1e-16f);
            out[(size_t)row * D + c] = h[(size_t)row * D + c] + acc[r] + bb * ws;
        }
    }
}

extern "C" void kernel_launch(void* const* d_in, const int* in_sizes, int n_in,
                              void* d_out, int out_size, void* d_ws, size_t ws_size,
                              hipStream_t stream)
{
    const float* h     = (const float*)d_in[0];
    const float* pos   = (const float*)d_in[1];
    const int*   ei    = (const int*)d_in[2];
    const float* eattr = (const float*)d_in[3];
    const float* Wq  = (const float*)d_in[4];  const float* bq  = (const float*)d_in[5];
    const float* Wk  = (const float*)d_in[6];  const float* bk  = (const float*)d_in[7];
    const float* Wv  = (const float*)d_in[8];  const float* bv  = (const float*)d_in[9];
    const float* We1 = (const float*)d_in[10]; const float* be1 = (const float*)d_in[11];
    const float* We2 = (const float*)d_in[12]; const float* be2 = (const float*)d_in[13];
    const float* Wa1 = (const float*)d_in[14]; const float* ba1 = (const float*)d_in[15];
    const float* Wa2 = (const float*)d_in[16]; const float* ba2 = (const float*)d_in[17];
    const float* Wm1 = (const float*)d_in[18]; const float* bm1 = (const float*)d_in[19];
    const float* Wm2 = (const float*)d_in[20]; const float* bm2 = (const float*)d_in[21];

    int N = in_sizes[0] / D;
    int E = in_sizes[3];
    int NB = (N + SB - 1) / SB;

    float* ws = (float*)d_ws;
    size_t off_f = 0;
    auto alloc = [&](size_t n) { float* p = ws + off_f; off_f += (n + 63) & ~(size_t)63; return p; };

    ushort* Wpk = (ushort*)alloc(24 * 4 * 64 * 8 / 2);   // 49152 bf16
    float* bqa = alloc(D); float* bka = alloc(D); float* bva = alloc(D);
    float* bounds = alloc(130);
    float2* AB = (float2*)alloc((size_t)129 * 128 * 2);
    float2* MB = (float2*)alloc((size_t)129 * 128 * 2);
    float* qa = alloc((size_t)N * D);
    unsigned* kv = (unsigned*)alloc((size_t)N * D);
    float* S  = qa;  // alias: wave reads qa row n before writing S row n
    float* segsum = alloc(N);
    int* deg  = (int*)alloc(N);
    int* offs = (int*)alloc(N);
    int* partial = (int*)alloc(256);
    int2* recs = (int2*)alloc((size_t)E * 2);

    int G0 = 517 + (N + 127) / 128;
    prep<<<G0, 128, 0, stream>>>(Wq, bq, Wk, bk, Wv, bv, Wa1, ba1, Wm1, bm1,
                                 We1, be1, We2, be2,
                                 Wpk, bqa, bka, bva, bounds, AB, MB, deg, N);

    // CSR build
    k_hist<<<(E + 255) / 256, 256, 0, stream>>>(ei, E, deg);
    k_scan1<<<NB, SB, 0, stream>>>(deg, N, partial);
    k_scan23<<<NB, SB, 0, stream>>>(deg, N, partial, NB, offs);
    k_scatter<<<(E + 255) / 256, 256, 0, stream>>>(ei, eattr, E, bounds, offs, recs);

    node_gemm<<<(N + 63) / 64, 256, 0, stream>>>(h, N, Wpk, bqa, bka, bva, qa, kv);

    node_all<<<(N + 7) / 8, 256, 0, stream>>>(recs, N, offs, qa, kv, AB, MB,
                                              Wa2, ba2, S, segsum);

    int G1 = (N + RPB - 1) / RPB;
    int G2 = (2 * N + 1023) / 1024;
    node_out<<<G1 + G2, 256, 0, stream>>>(h, N, S, Wm2, bm2, segsum, (float*)d_out,
                                          pos, 2 * N, G1);
}

// Round 7
// 253.836 us; speedup vs baseline: 9.5417x; 1.1800x over previous
//
#include <hip/hip_runtime.h>
#include <math.h>

#define D 128
#define SB 256

typedef __attribute__((ext_vector_type(8))) short bf16x8;
typedef __attribute__((ext_vector_type(4))) float f32x4;

// round-to-nearest-even f32 -> bf16 bits
__device__ inline unsigned f2bf(float f) {
    unsigned u = __float_as_uint(f);
    return (u + 0x7FFFu + ((u >> 16) & 1u)) >> 16;
}

// ---------------------------------------------------------------------------
// prep: one kernel for all precompute + histogram.
//   blocks [0,384)   : folded weights -> bf16 B-fragment-packed Wpk
//   blocks [384,387) : biases bqa/bka/bva (f32)
//   block  387       : global bounds[] (for k_scatter)
//   blocks [388,517) : interval tables AB/MB (recompute bounds locally)
//   blocks [517,645) : Wm2 -> bf16 B-fragment-packed Wpk2 (for node_out MFMA)
//   blocks 645+      : degree histogram (deg pre-zeroed by memsetAsync)
// ---------------------------------------------------------------------------
__global__ __launch_bounds__(128) void prep(
    const float* __restrict__ Wq, const float* __restrict__ bq,
    const float* __restrict__ Wk, const float* __restrict__ bk,
    const float* __restrict__ Wv, const float* __restrict__ bv,
    const float* __restrict__ Wa1, const float* __restrict__ ba1,
    const float* __restrict__ Wm1, const float* __restrict__ bm1,
    const float* __restrict__ We1, const float* __restrict__ be1,
    const float* __restrict__ We2, const float* __restrict__ be2,
    const float* __restrict__ Wm2,
    const int* __restrict__ ei, int E,
    ushort* __restrict__ Wpk, ushort* __restrict__ Wpk2,
    float* __restrict__ bqa, float* __restrict__ bka, float* __restrict__ bva,
    float* __restrict__ bounds,
    float2* __restrict__ AB, float2* __restrict__ MB,
    int* __restrict__ deg)
{
    int b = blockIdx.x;
    int j = threadIdx.x;
    if (b < 384) {
        int which = b >> 7, i = b & 127;   // i = k index
        const float *A, *B;
        if (which == 0)      { A = Wq; B = Wa1; }
        else if (which == 1) { A = Wk; B = Wa1 + 128 * D; }
        else                 { A = Wv; B = Wm1; }
        float acc = 0.f;
        for (int k = 0; k < D; k++) acc += A[i * D + k] * B[k * D + j];
        int gc = which * 128 + j;
        int nt = gc >> 4;
        int ks = i >> 5;
        int lane = (((i >> 3) & 3) << 4) | (gc & 15);
        int j8 = i & 7;
        Wpk[((nt * 4 + ks) * 64 + lane) * 8 + j8] = (ushort)f2bf(acc);
    } else if (b < 387) {
        int which = b - 384;
        const float *bias, *B, *extra; float *out;
        if (which == 0)      { bias = bq; B = Wa1;           out = bqa; extra = ba1; }
        else if (which == 1) { bias = bk; B = Wa1 + 128 * D; out = bka; extra = nullptr; }
        else                 { bias = bv; B = Wm1;           out = bva; extra = bm1; }
        float acc = extra ? extra[j] : 0.f;
        for (int k = 0; k < D; k++) acc += bias[k] * B[k * D + j];
        out[j] = acc;
    } else if (b == 387) {
        __shared__ float sb[128];
        float w = We1[j], bb = be1[j];
        float t = (w != 0.f) ? (-bb / w) : 2.f;
        t = fminf(fmaxf(t, 0.f), 1.f);
        sb[j] = t;
        __syncthreads();
        for (int k = 2; k <= 128; k <<= 1)
            for (int jj = k >> 1; jj > 0; jj >>= 1) {
                int ixj = j ^ jj;
                if (ixj > j) {
                    float a = sb[j], c = sb[ixj];
                    bool up = ((j & k) == 0);
                    if (up ? (a > c) : (a < c)) { sb[j] = c; sb[ixj] = a; }
                }
                __syncthreads();
            }
        if (j == 0) { bounds[0] = 0.f; bounds[129] = 1.f; }
        bounds[1 + j] = sb[j];
    } else if (b < 517) {
        // interval tables; recompute bounds locally to avoid cross-block dep
        __shared__ float sb[128];
        __shared__ float Ae[128], Be[128];
        float w = We1[j], bb = be1[j];
        float t = (w != 0.f) ? (-bb / w) : 2.f;
        t = fminf(fmaxf(t, 0.f), 1.f);
        sb[j] = t;
        __syncthreads();
        for (int k = 2; k <= 128; k <<= 1)
            for (int jj = k >> 1; jj > 0; jj >>= 1) {
                int ixj = j ^ jj;
                if (ixj > j) {
                    float a = sb[j], c = sb[ixj];
                    bool up = ((j & k) == 0);
                    if (up ? (a > c) : (a < c)) { sb[j] = c; sb[ixj] = a; }
                }
                __syncthreads();
            }
        int i = b - 388;                  // interval 0..128
        float lo = (i == 0)   ? 0.f : sb[i - 1];
        float hi = (i == 128) ? 1.f : sb[i];
        float m = 0.5f * (lo + hi);
        float ae = 0.f, be = 0.f;
        for (int k = 0; k < 128; k++) {
            float ww = We1[k], bb2 = be1[k];
            if (m * ww + bb2 > 0.f) { ae += ww * We2[k * D + j]; be += bb2 * We2[k * D + j]; }
        }
        be += be2[j];
        Ae[j] = ae; Be[j] = be;
        __syncthreads();
        float aa = 0.f, ba = 0.f, am = 0.f, bm = 0.f;
        for (int l = 0; l < 128; l++) {
            float ael = Ae[l], bel = Be[l];
            float wa = Wa1[(256 + l) * D + j];
            float wm = Wm1[(128 + l) * D + j];
            aa += ael * wa; ba += bel * wa;
            am += ael * wm; bm += bel * wm;
        }
        AB[i * 128 + j] = make_float2(aa, ba);
        MB[i * 128 + j] = make_float2(am, bm);
    } else if (b < 645) {
        int i = b - 517;                  // k row of Wm2
        int nt = j >> 4;
        int ks = i >> 5;
        int lane = (((i >> 3) & 3) << 4) | (j & 15);
        int j8 = i & 7;
        Wpk2[((nt * 4 + ks) * 64 + lane) * 8 + j8] = (ushort)f2bf(Wm2[i * D + j]);
    } else {
        int e = (b - 645) * 128 + j;
        if (e < E) atomicAdd(deg + ei[E + e], 1);
    }
}

// ---------------------------------------------------------------------------
// CSR scan: block sums -> fused scan (redundant partial-scan per block).
// off[] holds EXCLUSIVE starts; k_scatter bumps off[col] so afterwards
// off[n] = inclusive end of segment n.
// ---------------------------------------------------------------------------
__global__ __launch_bounds__(SB) void k_scan1(const int* __restrict__ deg, int N,
                                              int* __restrict__ partial)
{
    __shared__ int ls[SB];
    int t = threadIdx.x;
    int i = blockIdx.x * SB + t;
    ls[t] = (i < N) ? deg[i] : 0;
    __syncthreads();
    for (int s = SB / 2; s > 0; s >>= 1) {
        if (t < s) ls[t] += ls[t + s];
        __syncthreads();
    }
    if (t == 0) partial[blockIdx.x] = ls[0];
}

__global__ __launch_bounds__(SB) void k_scan23(const int* __restrict__ deg, int N,
                                               const int* __restrict__ partial, int NB,
                                               int* __restrict__ off)
{
    __shared__ int lp[SB];
    __shared__ int ls[SB];
    int t = threadIdx.x;
    int pv = (t < NB) ? partial[t] : 0;
    lp[t] = pv;
    __syncthreads();
    int pval = pv;
    for (int s = 1; s < SB; s <<= 1) {
        int add = (t >= s) ? lp[t - s] : 0;
        __syncthreads();
        pval += add;
        lp[t] = pval;
        __syncthreads();
    }
    int base = (blockIdx.x > 0) ? lp[blockIdx.x - 1] : 0;

    int i = blockIdx.x * SB + t;
    int v = (i < N) ? deg[i] : 0;
    ls[t] = v;
    __syncthreads();
    int val = v;
    for (int s = 1; s < SB; s <<= 1) {
        int add = (t >= s) ? ls[t - s] : 0;
        __syncthreads();
        val += add;
        ls[t] = val;
        __syncthreads();
    }
    if (i < N) off[i] = base + val - v;
}

// ---------------------------------------------------------------------------
// scatter_gemm: fused independent work in one grid.
//   blocks [0,GS)      : scatter packed records {row|interval<<17, bits(a)}
//   blocks [GS,GS+GG)  : MFMA node_gemm (verified R6 structure)
// ---------------------------------------------------------------------------
__global__ __launch_bounds__(256) void scatter_gemm(
    const int* __restrict__ ei, const float* __restrict__ eattr, int E,
    const float* __restrict__ bounds, int* __restrict__ off, int2* __restrict__ recs,
    int GS,
    const float* __restrict__ h, int N,
    const ushort* __restrict__ Wpk,
    const float* __restrict__ bqa, const float* __restrict__ bka, const float* __restrict__ bva,
    float* __restrict__ qa, unsigned* __restrict__ kv)
{
    __shared__ __align__(16) ushort hsb[64 * 128];
    __shared__ float bnd[130];
    int t = threadIdx.x;
    int blk = blockIdx.x;

    if (blk < GS) {
        if (t < 130) bnd[t] = bounds[t];
        __syncthreads();
        int e = blk * 256 + t;
        if (e >= E) return;
        int row = ei[e], col = ei[E + e];
        float a = eattr[e];
        int lo = 0, hi = 128;
        while (lo < hi) { int mid = (lo + hi + 1) >> 1; if (bnd[mid] <= a) lo = mid; else hi = mid - 1; }
        int p = atomicAdd(off + col, 1);
        recs[p] = make_int2(row | (lo << 17), __float_as_int(a));
        return;
    }

    int row0 = (blk - GS) * 64;
    // stage 64x128 f32 -> bf16, XOR-swizzled 16B granules
#pragma unroll
    for (int i = 0; i < 4; i++) {
        int g = t + i * 256;
        int r = g >> 4, c = g & 15;
        int grow = row0 + r;
        float4 f0, f1;
        if (grow < N) {
            const float4* hp = (const float4*)(h + (size_t)grow * D + c * 8);
            f0 = hp[0]; f1 = hp[1];
        } else {
            f0 = make_float4(0.f, 0.f, 0.f, 0.f); f1 = f0;
        }
        ushort u[8] = { (ushort)f2bf(f0.x), (ushort)f2bf(f0.y), (ushort)f2bf(f0.z), (ushort)f2bf(f0.w),
                        (ushort)f2bf(f1.x), (ushort)f2bf(f1.y), (ushort)f2bf(f1.z), (ushort)f2bf(f1.w) };
        int pc = c ^ (r & 15);
        *(uint4*)&hsb[r * 128 + pc * 8] = *(uint4*)u;
    }
    __syncthreads();

    int w = t >> 6, l = t & 63;
    int lrow = w * 16 + (l & 15);
    f32x4 acc[24];
#pragma unroll
    for (int i = 0; i < 24; i++) acc[i] = (f32x4){0.f, 0.f, 0.f, 0.f};

    const bf16x8* WB = (const bf16x8*)Wpk;
#pragma unroll
    for (int ks = 0; ks < 4; ks++) {
        int c = (ks * 4 + (l >> 4)) ^ (l & 15);
        bf16x8 afrag = *(const bf16x8*)&hsb[lrow * 128 + c * 8];
#pragma unroll
        for (int nt = 0; nt < 24; nt++) {
            bf16x8 bfrag = WB[(nt * 4 + ks) * 64 + l];
            acc[nt] = __builtin_amdgcn_mfma_f32_16x16x32_bf16(afrag, bfrag, acc[nt], 0, 0, 0);
        }
    }

    int rbase = row0 + w * 16 + ((l >> 4) << 2);
    int cl = l & 15;
#pragma unroll
    for (int cc = 0; cc < 8; cc++) {
        float bqv = bqa[cc * 16 + cl];
        float bkv = bka[cc * 16 + cl];
        float bvv = bva[cc * 16 + cl];
        f32x4 aq = acc[cc], ak = acc[8 + cc], av = acc[16 + cc];
#pragma unroll
        for (int r = 0; r < 4; r++) {
            int row = rbase + r;
            if (row < N) {
                qa[(size_t)row * D + cc * 16 + cl] = aq[r] + bqv;
                kv[(size_t)row * D + cc * 16 + cl] =
                    (f2bf(av[r] + bvv) << 16) | f2bf(ak[r] + bkv);
            }
        }
    }
}

// ---------------------------------------------------------------------------
// node_all: 32 lanes per destination node. Defer-max online softmax
// (rescale only when max grows by >8; exp(d)<=e^8 safe in f32; ba2 dropped —
// softmax is shift-invariant). 2-edge unroll batches 12 loads per pair.
// Emits S as packed bf16 pairs (for MFMA node_out) + segsum.
// ---------------------------------------------------------------------------
__global__ __launch_bounds__(256) void node_all(
    const int2* __restrict__ recs, int N,
    const int* __restrict__ off,
    const float* __restrict__ qa, const unsigned* __restrict__ kv,
    const float2* __restrict__ AB, const float2* __restrict__ MB,
    const float* __restrict__ Wa2,
    unsigned* __restrict__ Sb, float* __restrict__ segsum)
{
    int t = threadIdx.x;
    int l = t & 31;
    int n = blockIdx.x * 8 + (t >> 5);
    bool valid = (n < N);
    int start = 0, end = 0;
    if (valid) {
        end = off[n];
        start = (n > 0) ? off[n - 1] : 0;
    }

    const char* kvc = (const char*)kv;
    const char* ABc = (const char*)AB;
    const char* MBc = (const char*)MB;

    float4 q4 = valid ? *(const float4*)(qa + (size_t)n * D + 4 * l)
                      : make_float4(0.f, 0.f, 0.f, 0.f);
    float4 w4 = *(const float4*)(Wa2 + 4 * l);

    float m_run = -INFINITY;
    float a0 = 0.f, a1 = 0.f, a2 = 0.f, a3 = 0.f, ssum = 0.f;

    int idx = start;
    for (; idx + 2 <= end; idx += 2) {
        int2 rec1 = recs[idx];
        int2 rec2 = recs[idx + 1];
        unsigned u1 = (unsigned)rec1.x, u2 = (unsigned)rec2.x;
        float at1 = __int_as_float(rec1.y), at2 = __int_as_float(rec2.y);
        int rb1 = (int)(u1 & 0x1FFFFu) << 9, tb1 = (int)(u1 >> 17) << 10;
        int rb2 = (int)(u2 & 0x1FFFFu) << 9, tb2 = (int)(u2 >> 17) << 10;

        uint4 kp1 = *(const uint4*)(kvc + rb1 + (l << 4));
        uint4 kp2 = *(const uint4*)(kvc + rb2 + (l << 4));
        float4 ab0a = *(const float4*)(ABc + tb1 + (l << 5));
        float4 ab1a = *(const float4*)(ABc + tb1 + (l << 5) + 16);
        float4 mb0a = *(const float4*)(MBc + tb1 + (l << 5));
        float4 mb1a = *(const float4*)(MBc + tb1 + (l << 5) + 16);
        float4 ab0b = *(const float4*)(ABc + tb2 + (l << 5));
        float4 ab1b = *(const float4*)(ABc + tb2 + (l << 5) + 16);
        float4 mb0b = *(const float4*)(MBc + tb2 + (l << 5));
        float4 mb1b = *(const float4*)(MBc + tb2 + (l << 5) + 16);

        float p1 = fmaxf(q4.x + __uint_as_float(kp1.x << 16) + at1 * ab0a.x + ab0a.y, 0.f) * w4.x
                 + fmaxf(q4.y + __uint_as_float(kp1.y << 16) + at1 * ab0a.z + ab0a.w, 0.f) * w4.y
                 + fmaxf(q4.z + __uint_as_float(kp1.z << 16) + at1 * ab1a.x + ab1a.y, 0.f) * w4.z
                 + fmaxf(q4.w + __uint_as_float(kp1.w << 16) + at1 * ab1a.z + ab1a.w, 0.f) * w4.w;
        float p2 = fmaxf(q4.x + __uint_as_float(kp2.x << 16) + at2 * ab0b.x + ab0b.y, 0.f) * w4.x
                 + fmaxf(q4.y + __uint_as_float(kp2.y << 16) + at2 * ab0b.z + ab0b.w, 0.f) * w4.y
                 + fmaxf(q4.z + __uint_as_float(kp2.z << 16) + at2 * ab1b.x + ab1b.y, 0.f) * w4.z
                 + fmaxf(q4.w + __uint_as_float(kp2.w << 16) + at2 * ab1b.z + ab1b.w, 0.f) * w4.w;
#pragma unroll
        for (int s = 1; s < 32; s <<= 1) {
            p1 += __shfl_xor(p1, s, 64);
            p2 += __shfl_xor(p2, s, 64);
        }
        float d1 = p1 - m_run, d2 = p2 - m_run;
        if (fmaxf(d1, d2) > 8.f) {           // rare: max grew a lot (or first pair)
            float mN = fmaxf(fmaxf(p1, p2), m_run);
            float sc = __expf(m_run - mN);   // 0 on first pair
            a0 *= sc; a1 *= sc; a2 *= sc; a3 *= sc; ssum *= sc;
            m_run = mN; d1 = p1 - mN; d2 = p2 - mN;
        }
        float ex1 = __expf(d1), ex2 = __expf(d2);

        float x0 = __uint_as_float(kp1.x & 0xFFFF0000u) + at1 * mb0a.x + mb0a.y;
        float x1 = __uint_as_float(kp1.y & 0xFFFF0000u) + at1 * mb0a.z + mb0a.w;
        float x2 = __uint_as_float(kp1.z & 0xFFFF0000u) + at1 * mb1a.x + mb1a.y;
        float x3 = __uint_as_float(kp1.w & 0xFFFF0000u) + at1 * mb1a.z + mb1a.w;
        float y0 = __uint_as_float(kp2.x & 0xFFFF0000u) + at2 * mb0b.x + mb0b.y;
        float y1 = __uint_as_float(kp2.y & 0xFFFF0000u) + at2 * mb0b.z + mb0b.w;
        float y2 = __uint_as_float(kp2.z & 0xFFFF0000u) + at2 * mb1b.x + mb1b.y;
        float y3 = __uint_as_float(kp2.w & 0xFFFF0000u) + at2 * mb1b.z + mb1b.w;
        float s10 = x0 * __builtin_amdgcn_rcpf(1.f + __expf(-x0));
        float s11 = x1 * __builtin_amdgcn_rcpf(1.f + __expf(-x1));
        float s12 = x2 * __builtin_amdgcn_rcpf(1.f + __expf(-x2));
        float s13 = x3 * __builtin_amdgcn_rcpf(1.f + __expf(-x3));
        float s20 = y0 * __builtin_amdgcn_rcpf(1.f + __expf(-y0));
        float s21 = y1 * __builtin_amdgcn_rcpf(1.f + __expf(-y1));
        float s22 = y2 * __builtin_amdgcn_rcpf(1.f + __expf(-y2));
        float s23 = y3 * __builtin_amdgcn_rcpf(1.f + __expf(-y3));

        a0 = fmaf(ex2, s20, fmaf(ex1, s10, a0));
        a1 = fmaf(ex2, s21, fmaf(ex1, s11, a1));
        a2 = fmaf(ex2, s22, fmaf(ex1, s12, a2));
        a3 = fmaf(ex2, s23, fmaf(ex1, s13, a3));
        ssum += ex1 + ex2;
    }
    if (idx < end) {   // odd tail
        int2 rec = recs[idx];
        unsigned u1 = (unsigned)rec.x;
        float a = __int_as_float(rec.y);
        int rb = (int)(u1 & 0x1FFFFu) << 9, tb = (int)(u1 >> 17) << 10;
        uint4 kp = *(const uint4*)(kvc + rb + (l << 4));
        float4 ab0 = *(const float4*)(ABc + tb + (l << 5));
        float4 ab1 = *(const float4*)(ABc + tb + (l << 5) + 16);
        float4 mb0 = *(const float4*)(MBc + tb + (l << 5));
        float4 mb1 = *(const float4*)(MBc + tb + (l << 5) + 16);
        float p1 = fmaxf(q4.x + __uint_as_float(kp.x << 16) + a * ab0.x + ab0.y, 0.f) * w4.x
                 + fmaxf(q4.y + __uint_as_float(kp.y << 16) + a * ab0.z + ab0.w, 0.f) * w4.y
                 + fmaxf(q4.z + __uint_as_float(kp.z << 16) + a * ab1.x + ab1.y, 0.f) * w4.z
                 + fmaxf(q4.w + __uint_as_float(kp.w << 16) + a * ab1.z + ab1.w, 0.f) * w4.w;
#pragma unroll
        for (int s = 1; s < 32; s <<= 1) p1 += __shfl_xor(p1, s, 64);
        float d1 = p1 - m_run;
        if (d1 > 8.f) {
            float mN = p1;
            float sc = __expf(m_run - mN);
            a0 *= sc; a1 *= sc; a2 *= sc; a3 *= sc; ssum *= sc;
            m_run = mN; d1 = 0.f;
        }
        float ex = __expf(d1);
        float x0 = __uint_as_float(kp.x & 0xFFFF0000u) + a * mb0.x + mb0.y;
        float x1 = __uint_as_float(kp.y & 0xFFFF0000u) + a * mb0.z + mb0.w;
        float x2 = __uint_as_float(kp.z & 0xFFFF0000u) + a * mb1.x + mb1.y;
        float x3 = __uint_as_float(kp.w & 0xFFFF0000u) + a * mb1.z + mb1.w;
        a0 = fmaf(ex, x0 * __builtin_amdgcn_rcpf(1.f + __expf(-x0)), a0);
        a1 = fmaf(ex, x1 * __builtin_amdgcn_rcpf(1.f + __expf(-x1)), a1);
        a2 = fmaf(ex, x2 * __builtin_amdgcn_rcpf(1.f + __expf(-x2)), a2);
        a3 = fmaf(ex, x3 * __builtin_amdgcn_rcpf(1.f + __expf(-x3)), a3);
        ssum += ex;
    }

    if (valid) {
        float inv = __builtin_amdgcn_rcpf(ssum + 1e-16f);
        unsigned pw0 = f2bf(a0 * inv) | (f2bf(a1 * inv) << 16);
        unsigned pw1 = f2bf(a2 * inv) | (f2bf(a3 * inv) << 16);
        *(uint2*)(Sb + (size_t)n * 64 + 2 * l) = make_uint2(pw0, pw1);
        if (l == 0) segsum[n] = ssum;
    }
}

// ---------------------------------------------------------------------------
// node_out (MFMA): out = h + S@Wm2 + bm2 * (segsum/(segsum+1e-16)).
// S already bf16-packed; Wm2 B-frag packed by prep. Tail blocks copy pos.
// ---------------------------------------------------------------------------
__global__ __launch_bounds__(256) void node_out(
    const float* __restrict__ h, int N,
    const unsigned* __restrict__ Sb, const ushort* __restrict__ Wpk2,
    const float* __restrict__ bm2, const float* __restrict__ segsum,
    float* __restrict__ out, const float* __restrict__ pos, int npos, int G1)
{
    int b = blockIdx.x;
    int t = threadIdx.x;
    if (b >= G1) {
        int i = ((b - G1) * 256 + t) * 4;
        float* outp = out + (size_t)N * D;
        if (i + 3 < npos) {
            *(float4*)(outp + i) = *(const float4*)(pos + i);
        } else {
            for (int j = i; j < npos; j++) outp[j] = pos[j];
        }
        return;
    }
    __shared__ __align__(16) ushort ssb[64 * 128];
    int row0 = b * 64;
#pragma unroll
    for (int i = 0; i < 4; i++) {
        int g = t + i * 256;
        int r = g >> 4, c = g & 15;
        int grow = row0 + r;
        uint4 u = make_uint4(0u, 0u, 0u, 0u);
        if (grow < N) u = *(const uint4*)(Sb + (size_t)grow * 64 + c * 4);
        int pc = c ^ (r & 15);
        *(uint4*)&ssb[r * 128 + pc * 8] = u;
    }
    __syncthreads();

    int w = t >> 6, l = t & 63;
    int lrow = w * 16 + (l & 15);
    f32x4 acc[8];
#pragma unroll
    for (int i = 0; i < 8; i++) acc[i] = (f32x4){0.f, 0.f, 0.f, 0.f};

    const bf16x8* WB = (const bf16x8*)Wpk2;
#pragma unroll
    for (int ks = 0; ks < 4; ks++) {
        int c = (ks * 4 + (l >> 4)) ^ (l & 15);
        bf16x8 afrag = *(const bf16x8*)&ssb[lrow * 128 + c * 8];
#pragma unroll
        for (int nt = 0; nt < 8; nt++) {
            bf16x8 bfrag = WB[(nt * 4 + ks) * 64 + l];
            acc[nt] = __builtin_amdgcn_mfma_f32_16x16x32_bf16(afrag, bfrag, acc[nt], 0, 0, 0);
        }
    }

    int rbase = row0 + w * 16 + ((l >> 4) << 2);
    int cl = l & 15;
#pragma unroll
    for (int cc = 0; cc < 8; cc++) {
        float bb = bm2[cc * 16 + cl];
        f32x4 av = acc[cc];
#pragma unroll
        for (int r = 0; r < 4; r++) {
            int row = rbase + r;
            if (row < N) {
                float ws_ = segsum[row];
                ws_ = ws_ / (ws_ + 1e-16f);
                out[(size_t)row * D + cc * 16 + cl] =
                    h[(size_t)row * D + cc * 16 + cl] + av[r] + bb * ws_;
            }
        }
    }
}

extern "C" void kernel_launch(void* const* d_in, const int* in_sizes, int n_in,
                              void* d_out, int out_size, void* d_ws, size_t ws_size,
                              hipStream_t stream)
{
    const float* h     = (const float*)d_in[0];
    const float* pos   = (const float*)d_in[1];
    const int*   ei    = (const int*)d_in[2];
    const float* eattr = (const float*)d_in[3];
    const float* Wq  = (const float*)d_in[4];  const float* bq  = (const float*)d_in[5];
    const float* Wk  = (const float*)d_in[6];  const float* bk  = (const float*)d_in[7];
    const float* Wv  = (const float*)d_in[8];  const float* bv  = (const float*)d_in[9];
    const float* We1 = (const float*)d_in[10]; const float* be1 = (const float*)d_in[11];
    const float* We2 = (const float*)d_in[12]; const float* be2 = (const float*)d_in[13];
    const float* Wa1 = (const float*)d_in[14]; const float* ba1 = (const float*)d_in[15];
    const float* Wa2 = (const float*)d_in[16];
    const float* Wm1 = (const float*)d_in[18]; const float* bm1 = (const float*)d_in[19];
    const float* Wm2 = (const float*)d_in[20]; const float* bm2 = (const float*)d_in[21];

    int N = in_sizes[0] / D;
    int E = in_sizes[3];
    int NB = (N + SB - 1) / SB;

    float* ws = (float*)d_ws;
    size_t off_f = 0;
    auto alloc = [&](size_t n) { float* p = ws + off_f; off_f += (n + 63) & ~(size_t)63; return p; };

    ushort* Wpk  = (ushort*)alloc(24 * 4 * 64 * 8 / 2);
    ushort* Wpk2 = (ushort*)alloc(8 * 4 * 64 * 8 / 2);
    float* bqa = alloc(D); float* bka = alloc(D); float* bva = alloc(D);
    float* bounds = alloc(130);
    float2* AB = (float2*)alloc((size_t)129 * 128 * 2);
    float2* MB = (float2*)alloc((size_t)129 * 128 * 2);
    float* qa = alloc((size_t)N * D);
    unsigned* kv = (unsigned*)alloc((size_t)N * D);
    unsigned* Sb = (unsigned*)alloc((size_t)N * 64);
    float* segsum = alloc(N);
    int* deg  = (int*)alloc(N);
    int* offs = (int*)alloc(N);
    int* partial = (int*)alloc(256);
    int2* recs = (int2*)alloc((size_t)E * 2);

    hipMemsetAsync(deg, 0, (size_t)N * 4, stream);

    int HB = (E + 127) / 128;
    prep<<<645 + HB, 128, 0, stream>>>(Wq, bq, Wk, bk, Wv, bv, Wa1, ba1, Wm1, bm1,
                                       We1, be1, We2, be2, Wm2, ei, E,
                                       Wpk, Wpk2, bqa, bka, bva, bounds, AB, MB, deg);

    k_scan1<<<NB, SB, 0, stream>>>(deg, N, partial);
    k_scan23<<<NB, SB, 0, stream>>>(deg, N, partial, NB, offs);

    int GS = (E + 255) / 256;
    int GG = (N + 63) / 64;
    scatter_gemm<<<GS + GG, 256, 0, stream>>>(ei, eattr, E, bounds, offs, recs, GS,
                                              h, N, Wpk, bqa, bka, bva, qa, kv);

    node_all<<<(N + 7) / 8, 256, 0, stream>>>(recs, N, offs, qa, kv, AB, MB, Wa2,
                                              Sb, segsum);

    int G1 = (N + 63) / 64;
    int G2 = (2 * N + 1023) / 1024;
    node_out<<<G1 + G2, 256, 0, stream>>>(h, N, Sb, Wpk2, bm2, segsum, (float*)d_out,
                                          pos, 2 * N, G1);
}

// Round 8
// 251.264 us; speedup vs baseline: 9.6394x; 1.0102x over previous
//
#include <hip/hip_runtime.h>
#include <math.h>

#define D 128
#define SB 256

typedef __attribute__((ext_vector_type(8))) short bf16x8;
typedef __attribute__((ext_vector_type(4))) float f32x4;

// round-to-nearest-even f32 -> bf16 bits
__device__ inline unsigned f2bf(float f) {
    unsigned u = __float_as_uint(f);
    return (u + 0x7FFFu + ((u >> 16) & 1u)) >> 16;
}

// ---------------------------------------------------------------------------
// prep: one kernel for all precompute + histogram.
//   blocks [0,384)   : folded weights -> bf16 B-fragment-packed Wpk
//   blocks [384,387) : biases bqa/bka/bva (f32)
//   block  387       : global bounds[] (for k_scatter)
//   blocks [388,517) : interval tables AB/MB (recompute bounds locally)
//   blocks [517,645) : Wm2 -> bf16 B-fragment-packed Wpk2 (for node_out MFMA)
//   blocks 645+      : degree histogram (deg pre-zeroed by memsetAsync)
// ---------------------------------------------------------------------------
__global__ __launch_bounds__(128) void prep(
    const float* __restrict__ Wq, const float* __restrict__ bq,
    const float* __restrict__ Wk, const float* __restrict__ bk,
    const float* __restrict__ Wv, const float* __restrict__ bv,
    const float* __restrict__ Wa1, const float* __restrict__ ba1,
    const float* __restrict__ Wm1, const float* __restrict__ bm1,
    const float* __restrict__ We1, const float* __restrict__ be1,
    const float* __restrict__ We2, const float* __restrict__ be2,
    const float* __restrict__ Wm2,
    const int* __restrict__ ei, int E,
    ushort* __restrict__ Wpk, ushort* __restrict__ Wpk2,
    float* __restrict__ bqa, float* __restrict__ bka, float* __restrict__ bva,
    float* __restrict__ bounds,
    float2* __restrict__ AB, float2* __restrict__ MB,
    int* __restrict__ deg)
{
    int b = blockIdx.x;
    int j = threadIdx.x;
    if (b < 384) {
        int which = b >> 7, i = b & 127;   // i = k index
        const float *A, *B;
        if (which == 0)      { A = Wq; B = Wa1; }
        else if (which == 1) { A = Wk; B = Wa1 + 128 * D; }
        else                 { A = Wv; B = Wm1; }
        float acc = 0.f;
        for (int k = 0; k < D; k++) acc += A[i * D + k] * B[k * D + j];
        int gc = which * 128 + j;
        int nt = gc >> 4;
        int ks = i >> 5;
        int lane = (((i >> 3) & 3) << 4) | (gc & 15);
        int j8 = i & 7;
        Wpk[((nt * 4 + ks) * 64 + lane) * 8 + j8] = (ushort)f2bf(acc);
    } else if (b < 387) {
        int which = b - 384;
        const float *bias, *B, *extra; float *out;
        if (which == 0)      { bias = bq; B = Wa1;           out = bqa; extra = ba1; }
        else if (which == 1) { bias = bk; B = Wa1 + 128 * D; out = bka; extra = nullptr; }
        else                 { bias = bv; B = Wm1;           out = bva; extra = bm1; }
        float acc = extra ? extra[j] : 0.f;
        for (int k = 0; k < D; k++) acc += bias[k] * B[k * D + j];
        out[j] = acc;
    } else if (b == 387) {
        __shared__ float sb[128];
        float w = We1[j], bb = be1[j];
        float t = (w != 0.f) ? (-bb / w) : 2.f;
        t = fminf(fmaxf(t, 0.f), 1.f);
        sb[j] = t;
        __syncthreads();
        for (int k = 2; k <= 128; k <<= 1)
            for (int jj = k >> 1; jj > 0; jj >>= 1) {
                int ixj = j ^ jj;
                if (ixj > j) {
                    float a = sb[j], c = sb[ixj];
                    bool up = ((j & k) == 0);
                    if (up ? (a > c) : (a < c)) { sb[j] = c; sb[ixj] = a; }
                }
                __syncthreads();
            }
        if (j == 0) { bounds[0] = 0.f; bounds[129] = 1.f; }
        bounds[1 + j] = sb[j];
    } else if (b < 517) {
        // interval tables; recompute bounds locally to avoid cross-block dep
        __shared__ float sb[128];
        __shared__ float Ae[128], Be[128];
        float w = We1[j], bb = be1[j];
        float t = (w != 0.f) ? (-bb / w) : 2.f;
        t = fminf(fmaxf(t, 0.f), 1.f);
        sb[j] = t;
        __syncthreads();
        for (int k = 2; k <= 128; k <<= 1)
            for (int jj = k >> 1; jj > 0; jj >>= 1) {
                int ixj = j ^ jj;
                if (ixj > j) {
                    float a = sb[j], c = sb[ixj];
                    bool up = ((j & k) == 0);
                    if (up ? (a > c) : (a < c)) { sb[j] = c; sb[ixj] = a; }
                }
                __syncthreads();
            }
        int i = b - 388;                  // interval 0..128
        float lo = (i == 0)   ? 0.f : sb[i - 1];
        float hi = (i == 128) ? 1.f : sb[i];
        float m = 0.5f * (lo + hi);
        float ae = 0.f, be = 0.f;
        for (int k = 0; k < 128; k++) {
            float ww = We1[k], bb2 = be1[k];
            if (m * ww + bb2 > 0.f) { ae += ww * We2[k * D + j]; be += bb2 * We2[k * D + j]; }
        }
        be += be2[j];
        Ae[j] = ae; Be[j] = be;
        __syncthreads();
        float aa = 0.f, ba = 0.f, am = 0.f, bm = 0.f;
        for (int l = 0; l < 128; l++) {
            float ael = Ae[l], bel = Be[l];
            float wa = Wa1[(256 + l) * D + j];
            float wm = Wm1[(128 + l) * D + j];
            aa += ael * wa; ba += bel * wa;
            am += ael * wm; bm += bel * wm;
        }
        AB[i * 128 + j] = make_float2(aa, ba);
        MB[i * 128 + j] = make_float2(am, bm);
    } else if (b < 645) {
        int i = b - 517;                  // k row of Wm2
        int nt = j >> 4;
        int ks = i >> 5;
        int lane = (((i >> 3) & 3) << 4) | (j & 15);
        int j8 = i & 7;
        Wpk2[((nt * 4 + ks) * 64 + lane) * 8 + j8] = (ushort)f2bf(Wm2[i * D + j]);
    } else {
        int e = (b - 645) * 128 + j;
        if (e < E) atomicAdd(deg + ei[E + e], 1);
    }
}

// ---------------------------------------------------------------------------
// CSR scan: block sums -> fused scan (redundant partial-scan per block).
// off[] holds EXCLUSIVE starts; k_scatter bumps off[col] so afterwards
// off[n] = inclusive end of segment n.
// ---------------------------------------------------------------------------
__global__ __launch_bounds__(SB) void k_scan1(const int* __restrict__ deg, int N,
                                              int* __restrict__ partial)
{
    __shared__ int ls[SB];
    int t = threadIdx.x;
    int i = blockIdx.x * SB + t;
    ls[t] = (i < N) ? deg[i] : 0;
    __syncthreads();
    for (int s = SB / 2; s > 0; s >>= 1) {
        if (t < s) ls[t] += ls[t + s];
        __syncthreads();
    }
    if (t == 0) partial[blockIdx.x] = ls[0];
}

__global__ __launch_bounds__(SB) void k_scan23(const int* __restrict__ deg, int N,
                                               const int* __restrict__ partial, int NB,
                                               int* __restrict__ off)
{
    __shared__ int lp[SB];
    __shared__ int ls[SB];
    int t = threadIdx.x;
    int pv = (t < NB) ? partial[t] : 0;
    lp[t] = pv;
    __syncthreads();
    int pval = pv;
    for (int s = 1; s < SB; s <<= 1) {
        int add = (t >= s) ? lp[t - s] : 0;
        __syncthreads();
        pval += add;
        lp[t] = pval;
        __syncthreads();
    }
    int base = (blockIdx.x > 0) ? lp[blockIdx.x - 1] : 0;

    int i = blockIdx.x * SB + t;
    int v = (i < N) ? deg[i] : 0;
    ls[t] = v;
    __syncthreads();
    int val = v;
    for (int s = 1; s < SB; s <<= 1) {
        int add = (t >= s) ? ls[t - s] : 0;
        __syncthreads();
        val += add;
        ls[t] = val;
        __syncthreads();
    }
    if (i < N) off[i] = base + val - v;
}

// ---------------------------------------------------------------------------
// k_scatter: standalone (low VGPR, high occupancy — atomics hidden by TLP).
// Packs records {row | interval<<17, bits(a)} into CSR slots, bumping off[col].
// ---------------------------------------------------------------------------
__global__ __launch_bounds__(256) void k_scatter(const int* __restrict__ ei,
                                                 const float* __restrict__ eattr, int E,
                                                 const float* __restrict__ bounds,
                                                 int* __restrict__ off, int2* __restrict__ recs)
{
    __shared__ float bnd[130];
    int t = threadIdx.x;
    if (t < 130) bnd[t] = bounds[t];
    __syncthreads();
    int e = blockIdx.x * 256 + t;
    if (e >= E) return;
    int row = ei[e], col = ei[E + e];
    float a = eattr[e];
    int lo = 0, hi = 128;
    while (lo < hi) { int mid = (lo + hi + 1) >> 1; if (bnd[mid] <= a) lo = mid; else hi = mid - 1; }
    int p = atomicAdd(off + col, 1);
    recs[p] = make_int2(row | (lo << 17), __float_as_int(a));
}

// ---------------------------------------------------------------------------
// node_gemm (MFMA): [N x 128] @ [128 x 384] in bf16, f32 accum.
// h staged as bf16 in LDS with XOR-swizzled 16B granules. Epilogue writes
// qa (f32) and packed bf16 kv.
// ---------------------------------------------------------------------------
__global__ __launch_bounds__(256) void node_gemm(
    const float* __restrict__ h, int N,
    const ushort* __restrict__ Wpk,
    const float* __restrict__ bqa, const float* __restrict__ bka, const float* __restrict__ bva,
    float* __restrict__ qa, unsigned* __restrict__ kv)
{
    __shared__ __align__(16) ushort hsb[64 * 128];
    int t = threadIdx.x;
    int row0 = blockIdx.x * 64;
#pragma unroll
    for (int i = 0; i < 4; i++) {
        int g = t + i * 256;
        int r = g >> 4, c = g & 15;
        int grow = row0 + r;
        float4 f0, f1;
        if (grow < N) {
            const float4* hp = (const float4*)(h + (size_t)grow * D + c * 8);
            f0 = hp[0]; f1 = hp[1];
        } else {
            f0 = make_float4(0.f, 0.f, 0.f, 0.f); f1 = f0;
        }
        ushort u[8] = { (ushort)f2bf(f0.x), (ushort)f2bf(f0.y), (ushort)f2bf(f0.z), (ushort)f2bf(f0.w),
                        (ushort)f2bf(f1.x), (ushort)f2bf(f1.y), (ushort)f2bf(f1.z), (ushort)f2bf(f1.w) };
        int pc = c ^ (r & 15);
        *(uint4*)&hsb[r * 128 + pc * 8] = *(uint4*)u;
    }
    __syncthreads();

    int w = t >> 6, l = t & 63;
    int lrow = w * 16 + (l & 15);
    f32x4 acc[24];
#pragma unroll
    for (int i = 0; i < 24; i++) acc[i] = (f32x4){0.f, 0.f, 0.f, 0.f};

    const bf16x8* WB = (const bf16x8*)Wpk;
#pragma unroll
    for (int ks = 0; ks < 4; ks++) {
        int c = (ks * 4 + (l >> 4)) ^ (l & 15);
        bf16x8 afrag = *(const bf16x8*)&hsb[lrow * 128 + c * 8];
#pragma unroll
        for (int nt = 0; nt < 24; nt++) {
            bf16x8 bfrag = WB[(nt * 4 + ks) * 64 + l];
            acc[nt] = __builtin_amdgcn_mfma_f32_16x16x32_bf16(afrag, bfrag, acc[nt], 0, 0, 0);
        }
    }

    int rbase = row0 + w * 16 + ((l >> 4) << 2);
    int cl = l & 15;
#pragma unroll
    for (int cc = 0; cc < 8; cc++) {
        float bqv = bqa[cc * 16 + cl];
        float bkv = bka[cc * 16 + cl];
        float bvv = bva[cc * 16 + cl];
        f32x4 aq = acc[cc], ak = acc[8 + cc], av = acc[16 + cc];
#pragma unroll
        for (int r = 0; r < 4; r++) {
            int row = rbase + r;
            if (row < N) {
                qa[(size_t)row * D + cc * 16 + cl] = aq[r] + bqv;
                kv[(size_t)row * D + cc * 16 + cl] =
                    (f2bf(av[r] + bvv) << 16) | f2bf(ak[r] + bkv);
            }
        }
    }
}

// ---------------------------------------------------------------------------
// node_all: 32 lanes per destination node. Defer-max online softmax
// (rescale only when max grows by >8; ba2 dropped — shift-invariant).
// 2-edge unroll batches 12 loads per pair. Emits bf16-packed S + segsum.
// ---------------------------------------------------------------------------
__global__ __launch_bounds__(256) void node_all(
    const int2* __restrict__ recs, int N,
    const int* __restrict__ off,
    const float* __restrict__ qa, const unsigned* __restrict__ kv,
    const float2* __restrict__ AB, const float2* __restrict__ MB,
    const float* __restrict__ Wa2,
    unsigned* __restrict__ Sb, float* __restrict__ segsum)
{
    int t = threadIdx.x;
    int l = t & 31;
    int n = blockIdx.x * 8 + (t >> 5);
    bool valid = (n < N);
    int start = 0, end = 0;
    if (valid) {
        end = off[n];
        start = (n > 0) ? off[n - 1] : 0;
    }

    const char* kvc = (const char*)kv;
    const char* ABc = (const char*)AB;
    const char* MBc = (const char*)MB;

    float4 q4 = valid ? *(const float4*)(qa + (size_t)n * D + 4 * l)
                      : make_float4(0.f, 0.f, 0.f, 0.f);
    float4 w4 = *(const float4*)(Wa2 + 4 * l);

    float m_run = -INFINITY;
    float a0 = 0.f, a1 = 0.f, a2 = 0.f, a3 = 0.f, ssum = 0.f;

    int idx = start;
    for (; idx + 2 <= end; idx += 2) {
        int2 rec1 = recs[idx];
        int2 rec2 = recs[idx + 1];
        unsigned u1 = (unsigned)rec1.x, u2 = (unsigned)rec2.x;
        float at1 = __int_as_float(rec1.y), at2 = __int_as_float(rec2.y);
        int rb1 = (int)(u1 & 0x1FFFFu) << 9, tb1 = (int)(u1 >> 17) << 10;
        int rb2 = (int)(u2 & 0x1FFFFu) << 9, tb2 = (int)(u2 >> 17) << 10;

        uint4 kp1 = *(const uint4*)(kvc + rb1 + (l << 4));
        uint4 kp2 = *(const uint4*)(kvc + rb2 + (l << 4));
        float4 ab0a = *(const float4*)(ABc + tb1 + (l << 5));
        float4 ab1a = *(const float4*)(ABc + tb1 + (l << 5) + 16);
        float4 mb0a = *(const float4*)(MBc + tb1 + (l << 5));
        float4 mb1a = *(const float4*)(MBc + tb1 + (l << 5) + 16);
        float4 ab0b = *(const float4*)(ABc + tb2 + (l << 5));
        float4 ab1b = *(const float4*)(ABc + tb2 + (l << 5) + 16);
        float4 mb0b = *(const float4*)(MBc + tb2 + (l << 5));
        float4 mb1b = *(const float4*)(MBc + tb2 + (l << 5) + 16);

        float p1 = fmaxf(q4.x + __uint_as_float(kp1.x << 16) + at1 * ab0a.x + ab0a.y, 0.f) * w4.x
                 + fmaxf(q4.y + __uint_as_float(kp1.y << 16) + at1 * ab0a.z + ab0a.w, 0.f) * w4.y
                 + fmaxf(q4.z + __uint_as_float(kp1.z << 16) + at1 * ab1a.x + ab1a.y, 0.f) * w4.z
                 + fmaxf(q4.w + __uint_as_float(kp1.w << 16) + at1 * ab1a.z + ab1a.w, 0.f) * w4.w;
        float p2 = fmaxf(q4.x + __uint_as_float(kp2.x << 16) + at2 * ab0b.x + ab0b.y, 0.f) * w4.x
                 + fmaxf(q4.y + __uint_as_float(kp2.y << 16) + at2 * ab0b.z + ab0b.w, 0.f) * w4.y
                 + fmaxf(q4.z + __uint_as_float(kp2.z << 16) + at2 * ab1b.x + ab1b.y, 0.f) * w4.z
                 + fmaxf(q4.w + __uint_as_float(kp2.w << 16) + at2 * ab1b.z + ab1b.w, 0.f) * w4.w;
#pragma unroll
        for (int s = 1; s < 32; s <<= 1) {
            p1 += __shfl_xor(p1, s, 64);
            p2 += __shfl_xor(p2, s, 64);
        }
        float d1 = p1 - m_run, d2 = p2 - m_run;
        if (fmaxf(d1, d2) > 8.f) {           // rare: max grew a lot (or first pair)
            float mN = fmaxf(fmaxf(p1, p2), m_run);
            float sc = __expf(m_run - mN);   // 0 on first pair
            a0 *= sc; a1 *= sc; a2 *= sc; a3 *= sc; ssum *= sc;
            m_run = mN; d1 = p1 - mN; d2 = p2 - mN;
        }
        float ex1 = __expf(d1), ex2 = __expf(d2);

        float x0 = __uint_as_float(kp1.x & 0xFFFF0000u) + at1 * mb0a.x + mb0a.y;
        float x1 = __uint_as_float(kp1.y & 0xFFFF0000u) + at1 * mb0a.z + mb0a.w;
        float x2 = __uint_as_float(kp1.z & 0xFFFF0000u) + at1 * mb1a.x + mb1a.y;
        float x3 = __uint_as_float(kp1.w & 0xFFFF0000u) + at1 * mb1a.z + mb1a.w;
        float y0 = __uint_as_float(kp2.x & 0xFFFF0000u) + at2 * mb0b.x + mb0b.y;
        float y1 = __uint_as_float(kp2.y & 0xFFFF0000u) + at2 * mb0b.z + mb0b.w;
        float y2 = __uint_as_float(kp2.z & 0xFFFF0000u) + at2 * mb1b.x + mb1b.y;
        float y3 = __uint_as_float(kp2.w & 0xFFFF0000u) + at2 * mb1b.z + mb1b.w;
        float s10 = x0 * __builtin_amdgcn_rcpf(1.f + __expf(-x0));
        float s11 = x1 * __builtin_amdgcn_rcpf(1.f + __expf(-x1));
        float s12 = x2 * __builtin_amdgcn_rcpf(1.f + __expf(-x2));
        float s13 = x3 * __builtin_amdgcn_rcpf(1.f + __expf(-x3));
        float s20 = y0 * __builtin_amdgcn_rcpf(1.f + __expf(-y0));
        float s21 = y1 * __builtin_amdgcn_rcpf(1.f + __expf(-y1));
        float s22 = y2 * __builtin_amdgcn_rcpf(1.f + __expf(-y2));
        float s23 = y3 * __builtin_amdgcn_rcpf(1.f + __expf(-y3));

        a0 = fmaf(ex2, s20, fmaf(ex1, s10, a0));
        a1 = fmaf(ex2, s21, fmaf(ex1, s11, a1));
        a2 = fmaf(ex2, s22, fmaf(ex1, s12, a2));
        a3 = fmaf(ex2, s23, fmaf(ex1, s13, a3));
        ssum += ex1 + ex2;
    }
    if (idx < end) {   // odd tail
        int2 rec = recs[idx];
        unsigned u1 = (unsigned)rec.x;
        float a = __int_as_float(rec.y);
        int rb = (int)(u1 & 0x1FFFFu) << 9, tb = (int)(u1 >> 17) << 10;
        uint4 kp = *(const uint4*)(kvc + rb + (l << 4));
        float4 ab0 = *(const float4*)(ABc + tb + (l << 5));
        float4 ab1 = *(const float4*)(ABc + tb + (l << 5) + 16);
        float4 mb0 = *(const float4*)(MBc + tb + (l << 5));
        float4 mb1 = *(const float4*)(MBc + tb + (l << 5) + 16);
        float p1 = fmaxf(q4.x + __uint_as_float(kp.x << 16) + a * ab0.x + ab0.y, 0.f) * w4.x
                 + fmaxf(q4.y + __uint_as_float(kp.y << 16) + a * ab0.z + ab0.w, 0.f) * w4.y
                 + fmaxf(q4.z + __uint_as_float(kp.z << 16) + a * ab1.x + ab1.y, 0.f) * w4.z
                 + fmaxf(q4.w + __uint_as_float(kp.w << 16) + a * ab1.z + ab1.w, 0.f) * w4.w;
#pragma unroll
        for (int s = 1; s < 32; s <<= 1) p1 += __shfl_xor(p1, s, 64);
        float d1 = p1 - m_run;
        if (d1 > 8.f) {
            float mN = p1;
            float sc = __expf(m_run - mN);
            a0 *= sc; a1 *= sc; a2 *= sc; a3 *= sc; ssum *= sc;
            m_run = mN; d1 = 0.f;
        }
        float ex = __expf(d1);
        float x0 = __uint_as_float(kp.x & 0xFFFF0000u) + a * mb0.x + mb0.y;
        float x1 = __uint_as_float(kp.y & 0xFFFF0000u) + a * mb0.z + mb0.w;
        float x2 = __uint_as_float(kp.z & 0xFFFF0000u) + a * mb1.x + mb1.y;
        float x3 = __uint_as_float(kp.w & 0xFFFF0000u) + a * mb1.z + mb1.w;
        a0 = fmaf(ex, x0 * __builtin_amdgcn_rcpf(1.f + __expf(-x0)), a0);
        a1 = fmaf(ex, x1 * __builtin_amdgcn_rcpf(1.f + __expf(-x1)), a1);
        a2 = fmaf(ex, x2 * __builtin_amdgcn_rcpf(1.f + __expf(-x2)), a2);
        a3 = fmaf(ex, x3 * __builtin_amdgcn_rcpf(1.f + __expf(-x3)), a3);
        ssum += ex;
    }

    if (valid) {
        float inv = __builtin_amdgcn_rcpf(ssum + 1e-16f);
        unsigned pw0 = f2bf(a0 * inv) | (f2bf(a1 * inv) << 16);
        unsigned pw1 = f2bf(a2 * inv) | (f2bf(a3 * inv) << 16);
        *(uint2*)(Sb + (size_t)n * 64 + 2 * l) = make_uint2(pw0, pw1);
        if (l == 0) segsum[n] = ssum;
    }
}

// ---------------------------------------------------------------------------
// node_out (MFMA): out = h + S@Wm2 + bm2 * (segsum/(segsum+1e-16)).
// S already bf16-packed; Wm2 B-frag packed by prep. Tail blocks copy pos.
// ---------------------------------------------------------------------------
__global__ __launch_bounds__(256) void node_out(
    const float* __restrict__ h, int N,
    const unsigned* __restrict__ Sb, const ushort* __restrict__ Wpk2,
    const float* __restrict__ bm2, const float* __restrict__ segsum,
    float* __restrict__ out, const float* __restrict__ pos, int npos, int G1)
{
    int b = blockIdx.x;
    int t = threadIdx.x;
    if (b >= G1) {
        int i = ((b - G1) * 256 + t) * 4;
        float* outp = out + (size_t)N * D;
        if (i + 3 < npos) {
            *(float4*)(outp + i) = *(const float4*)(pos + i);
        } else {
            for (int j = i; j < npos; j++) outp[j] = pos[j];
        }
        return;
    }
    __shared__ __align__(16) ushort ssb[64 * 128];
    int row0 = b * 64;
#pragma unroll
    for (int i = 0; i < 4; i++) {
        int g = t + i * 256;
        int r = g >> 4, c = g & 15;
        int grow = row0 + r;
        uint4 u = make_uint4(0u, 0u, 0u, 0u);
        if (grow < N) u = *(const uint4*)(Sb + (size_t)grow * 64 + c * 4);
        int pc = c ^ (r & 15);
        *(uint4*)&ssb[r * 128 + pc * 8] = u;
    }
    __syncthreads();

    int w = t >> 6, l = t & 63;
    int lrow = w * 16 + (l & 15);
    f32x4 acc[8];
#pragma unroll
    for (int i = 0; i < 8; i++) acc[i] = (f32x4){0.f, 0.f, 0.f, 0.f};

    const bf16x8* WB = (const bf16x8*)Wpk2;
#pragma unroll
    for (int ks = 0; ks < 4; ks++) {
        int c = (ks * 4 + (l >> 4)) ^ (l & 15);
        bf16x8 afrag = *(const bf16x8*)&ssb[lrow * 128 + c * 8];
#pragma unroll
        for (int nt = 0; nt < 8; nt++) {
            bf16x8 bfrag = WB[(nt * 4 + ks) * 64 + l];
            acc[nt] = __builtin_amdgcn_mfma_f32_16x16x32_bf16(afrag, bfrag, acc[nt], 0, 0, 0);
        }
    }

    int rbase = row0 + w * 16 + ((l >> 4) << 2);
    int cl = l & 15;
#pragma unroll
    for (int cc = 0; cc < 8; cc++) {
        float bb = bm2[cc * 16 + cl];
        f32x4 av = acc[cc];
#pragma unroll
        for (int r = 0; r < 4; r++) {
            int row = rbase + r;
            if (row < N) {
                float ws_ = segsum[row];
                ws_ = ws_ / (ws_ + 1e-16f);
                out[(size_t)row * D + cc * 16 + cl] =
                    h[(size_t)row * D + cc * 16 + cl] + av[r] + bb * ws_;
            }
        }
    }
}

extern "C" void kernel_launch(void* const* d_in, const int* in_sizes, int n_in,
                              void* d_out, int out_size, void* d_ws, size_t ws_size,
                              hipStream_t stream)
{
    const float* h     = (const float*)d_in[0];
    const float* pos   = (const float*)d_in[1];
    const int*   ei    = (const int*)d_in[2];
    const float* eattr = (const float*)d_in[3];
    const float* Wq  = (const float*)d_in[4];  const float* bq  = (const float*)d_in[5];
    const float* Wk  = (const float*)d_in[6];  const float* bk  = (const float*)d_in[7];
    const float* Wv  = (const float*)d_in[8];  const float* bv  = (const float*)d_in[9];
    const float* We1 = (const float*)d_in[10]; const float* be1 = (const float*)d_in[11];
    const float* We2 = (const float*)d_in[12]; const float* be2 = (const float*)d_in[13];
    const float* Wa1 = (const float*)d_in[14]; const float* ba1 = (const float*)d_in[15];
    const float* Wa2 = (const float*)d_in[16];
    const float* Wm1 = (const float*)d_in[18]; const float* bm1 = (const float*)d_in[19];
    const float* Wm2 = (const float*)d_in[20]; const float* bm2 = (const float*)d_in[21];

    int N = in_sizes[0] / D;
    int E = in_sizes[3];
    int NB = (N + SB - 1) / SB;

    float* ws = (float*)d_ws;
    size_t off_f = 0;
    auto alloc = [&](size_t n) { float* p = ws + off_f; off_f += (n + 63) & ~(size_t)63; return p; };

    ushort* Wpk  = (ushort*)alloc(24 * 4 * 64 * 8 / 2);
    ushort* Wpk2 = (ushort*)alloc(8 * 4 * 64 * 8 / 2);
    float* bqa = alloc(D); float* bka = alloc(D); float* bva = alloc(D);
    float* bounds = alloc(130);
    float2* AB = (float2*)alloc((size_t)129 * 128 * 2);
    float2* MB = (float2*)alloc((size_t)129 * 128 * 2);
    float* qa = alloc((size_t)N * D);
    unsigned* kv = (unsigned*)alloc((size_t)N * D);
    unsigned* Sb = (unsigned*)alloc((size_t)N * 64);
    float* segsum = alloc(N);
    int* deg  = (int*)alloc(N);
    int* offs = (int*)alloc(N);
    int* partial = (int*)alloc(256);
    int2* recs = (int2*)alloc((size_t)E * 2);

    hipMemsetAsync(deg, 0, (size_t)N * 4, stream);

    int HB = (E + 127) / 128;
    prep<<<645 + HB, 128, 0, stream>>>(Wq, bq, Wk, bk, Wv, bv, Wa1, ba1, Wm1, bm1,
                                       We1, be1, We2, be2, Wm2, ei, E,
                                       Wpk, Wpk2, bqa, bka, bva, bounds, AB, MB, deg);

    k_scan1<<<NB, SB, 0, stream>>>(deg, N, partial);
    k_scan23<<<NB, SB, 0, stream>>>(deg, N, partial, NB, offs);

    node_gemm<<<(N + 63) / 64, 256, 0, stream>>>(h, N, Wpk, bqa, bka, bva, qa, kv);

    k_scatter<<<(E + 255) / 256, 256, 0, stream>>>(ei, eattr, E, bounds, offs, recs);

    node_all<<<(N + 7) / 8, 256, 0, stream>>>(recs, N, offs, qa, kv, AB, MB, Wa2,
                                              Sb, segsum);

    int G1 = (N + 63) / 64;
    int G2 = (2 * N + 1023) / 1024;
    node_out<<<G1 + G2, 256, 0, stream>>>(h, N, Sb, Wpk2, bm2, segsum, (float*)d_out,
                                          pos, 2 * N, G1);
}